// Round 18
// baseline (1724.104 us; speedup 1.0000x reference)
//
#include <hip/hip_runtime.h>
#include <math.h>

#define T_STEPS 64
#define BATCH   128
#define TBTOT   8192

typedef __attribute__((ext_vector_type(8))) short bf16x8;
typedef __attribute__((ext_vector_type(4))) float f32x4;

// ---------------- workspace layout (float offsets) ----------------
// NOTE region lifetimes: [0,12845056) holds convAh/convAl during conv+fc, then is
// reused for LSTM fragments + state. State init MUST run after the fc GEMM.
static const size_t OFF_CONVH  = 0;              // [8192*1568] bf16 hi
static const size_t OFF_CONVL  = 6422528;        // [8192*1568] bf16 lo
static const size_t OFF_MWFHI  = 0;              // [4096*1024] bf16 (phase 2)
static const size_t OFF_MWFLO  = 2097152;
static const size_t OFF_EWFHI  = 4194304;        // [1024*256] bf16
static const size_t OFF_EWFLO  = 4325376;
static const size_t OFF_HBMHI  = 4456448;        // [2][128][1024] bf16
static const size_t OFF_HBMLO  = 4587520;
static const size_t OFF_HBEHI  = 4718592;        // [2][128][256] bf16
static const size_t OFF_HBELO  = 4734976;
static const size_t OFF_CBM    = 4767744;        // [128][1024] f32
static const size_t OFF_CBE    = 4898816;        // [128][256] f32
static const size_t OFF_WIHFH  = 4931584;        // [4096*288] bf16
static const size_t OFF_WIHFL  = 5521408;
static const size_t OFF_IMGH   = 12845056;       // [8192][256]
static const size_t OFF_LANGIN = 14942208;       // [8192][32]
static const size_t OFF_ENCXW  = 15204352;       // [8192][1024]
static const size_t OFF_ENCHS  = 23592960;       // [8192][256]
static const size_t OFF_LANGH  = 25690112;       // [8192][32]
static const size_t OFF_HIDH   = 25952256;       // [8192*288] bf16 hi
static const size_t OFF_HIDL   = 27131904;       // [8192*288] bf16 lo
static const size_t OFF_MEMXW  = 28311552;       // [8192][4096]
static const size_t OFF_CW2H   = 28311552;       // 5120 shorts
static const size_t OFF_CW2L   = 28314112;
static const size_t OFF_CW3H   = 28316672;       // 9216 shorts
static const size_t OFF_CW3L   = 28321280;
static const size_t OFF_FCWH   = 28325888;       // [256*1568] bf16
static const size_t OFF_FCWL   = 28526592;
static const size_t OFF_MEMHS  = 61865984;       // [8192][1024]
static const size_t OFF_ENCBC  = 70582272;       // [1024]
static const size_t OFF_MEMBC  = 70583296;       // [4096]
static const size_t OFF_HEADW  = 70587392;       // [16][1024]
static const size_t OFF_HEADB  = 70603776;       // [16]

__device__ __forceinline__ float fast_sigm(float x) { return 1.0f / (1.0f + __expf(-x)); }
__device__ __forceinline__ float fast_tanh(float x) { return 2.0f / (1.0f + __expf(-2.0f * x)) - 1.0f; }

__device__ __forceinline__ short f32_to_bf16_rne(float x) {
    unsigned u = __float_as_uint(x);
    unsigned r = (u + 0x7fffu + ((u >> 16) & 1u)) >> 16;
    return (short)r;
}
__device__ __forceinline__ float bf16s_to_f32(short s) {
    return __uint_as_float(((unsigned)(unsigned short)s) << 16);
}

// ---------------- prep ----------------
__global__ void prep_kernel(const float* __restrict__ enc_bih, const float* __restrict__ enc_bhh,
                            const float* __restrict__ mem_bih, const float* __restrict__ mem_bhh,
                            const float* __restrict__ actor_w, const float* __restrict__ actor_b,
                            const float* __restrict__ critic_w, const float* __restrict__ critic_b,
                            float* __restrict__ enc_bc, float* __restrict__ mem_bc,
                            float* __restrict__ head_w, float* __restrict__ head_b) {
    int g = blockIdx.x * 256 + threadIdx.x;
    if (g < 1024)  enc_bc[g] = enc_bih[g] + enc_bhh[g];
    if (g < 4096)  mem_bc[g] = mem_bih[g] + mem_bhh[g];
    if (g < 16384) { int j = g >> 10, k = g & 1023; head_w[g] = (j < 15) ? actor_w[j * 1024 + k] : critic_w[k]; }
    if (g < 16)    head_b[g] = (g < 15) ? actor_b[g] : critic_b[0];
}

// ---------------- init LSTM state (runs AFTER fc GEMM frees the region) ----------------
__global__ void init_state_kernel(const float* __restrict__ h0, const float* __restrict__ c0,
                                  short* __restrict__ hhi, short* __restrict__ hlo,
                                  float* __restrict__ cb, int n) {
    int g = blockIdx.x * 256 + threadIdx.x;
    if (g < n) {
        float v = h0[g];
        short a = f32_to_bf16_rne(v);
        hhi[g] = a;
        hlo[g] = f32_to_bf16_rne(v - bf16s_to_f32(a));
        cb[g] = c0[g];
    }
}

// ---------------- split Whh into MFMA-fragment-ordered bf16 hi/lo ----------------
__global__ void split_frag_kernel(const float* __restrict__ W, short* __restrict__ hi,
                                  short* __restrict__ lo, int H) {
    size_t f = (size_t)blockIdx.x * 256 + threadIdx.x;
    size_t total = (size_t)4 * H * H;
    if (f >= total) return;
    int e    = (int)(f & 7);
    int lane = (int)((f >> 3) & 63);
    size_t rest = f >> 9;
    int nks = H >> 5;
    int ks  = (int)(rest % nks);
    int qjt = (int)(rest / nks);
    int njt = H >> 4;
    int qq = qjt / njt, jt = qjt - qq * njt;
    int n = qq * H + jt * 16 + (lane & 15);
    int k = ks * 32 + (lane >> 4) * 8 + e;
    float w = W[(size_t)n * H + k];
    short a = f32_to_bf16_rne(w);
    short b = f32_to_bf16_rne(w - bf16s_to_f32(a));
    hi[f] = a; lo[f] = b;
}

// ---------------- generic GEMM weight frags (row-major K) ----------------
__global__ void gemm_frag_kernel(const float* __restrict__ W, short* __restrict__ hi,
                                 short* __restrict__ lo, int Kv, int nks, int ntot) {
    int f = blockIdx.x * 256 + threadIdx.x;
    int total = ntot * nks * 512;
    if (f >= total) return;
    int e    = f & 7;
    int lane = (f >> 3) & 63;
    int rest = f >> 9;
    int ks   = rest % nks;
    int nt   = rest / nks;
    int n = nt * 16 + (lane & 15);
    int k = ks * 32 + (lane >> 4) * 8 + e;
    float w = (k < Kv) ? W[(size_t)n * Kv + k] : 0.0f;
    short a = f32_to_bf16_rne(w);
    short b = f32_to_bf16_rne(w - bf16s_to_f32(a));
    hi[f] = a; lo[f] = b;
}

// ---------------- conv weight frags, TAP-MAJOR permuted K: k' = tap*ICN + ic ----------------
__global__ void conv_frag_perm_kernel(const float* __restrict__ W, short* __restrict__ hi,
                                      short* __restrict__ lo, int ICN, int nks) {
    int f = blockIdx.x * 256 + threadIdx.x;
    int total = 2 * nks * 512;
    if (f >= total) return;
    int e    = f & 7;
    int lane = (f >> 3) & 63;
    int rest = f >> 9;
    int ks   = rest % nks;
    int nt   = rest / nks;
    int n  = nt * 16 + (lane & 15);
    int kp = ks * 32 + (lane >> 4) * 8 + e;
    int Kv = ICN * 9;
    float w = 0.0f;
    if (kp < Kv) {
        int tap = kp / ICN, ic = kp % ICN;
        w = W[(size_t)n * Kv + ic * 9 + tap];
    }
    short a = f32_to_bf16_rne(w);
    short b = f32_to_bf16_rne(w - bf16s_to_f32(a));
    hi[f] = a; lo[f] = b;
}

// ---------------- MFMA split-bf16 GEMM, 64x64 tile ----------------
template <bool RELU>
__global__ __launch_bounds__(256) void mfma_gemm(
        const short* __restrict__ Ah, const short* __restrict__ Al,
        const short* __restrict__ Wfh, const short* __restrict__ Wfl,
        const float* __restrict__ bias, float* __restrict__ C,
        int N, int K, int KS) {
    const int t = threadIdx.x, lane = t & 63, wv = t >> 6;
    const int m0 = blockIdx.x * 64, n0 = blockIdx.y * 64;
    const int pr = m0 + wv * 16 + (lane & 15);
    const size_t abase = (size_t)pr * K + ((lane >> 4) << 3);
    const int ntg0 = n0 >> 4;
    f32x4 acc0 = {0.f,0.f,0.f,0.f}, acc1 = {0.f,0.f,0.f,0.f};
    f32x4 acc2 = {0.f,0.f,0.f,0.f}, acc3 = {0.f,0.f,0.f,0.f};
    for (int ks = 0; ks < KS; ++ks) {
        bf16x8 ah = *(const bf16x8*)&Ah[abase + (size_t)ks * 32];
        bf16x8 al = *(const bf16x8*)&Al[abase + (size_t)ks * 32];
        const bf16x8* bh0 = (const bf16x8*)Wfh + ((size_t)ntg0 * KS + ks) * 64 + lane;
        const bf16x8* bl0 = (const bf16x8*)Wfl + ((size_t)ntg0 * KS + ks) * 64 + lane;
        bf16x8 bh, bl;
        bh = bh0[0];            bl = bl0[0];
        acc0 = __builtin_amdgcn_mfma_f32_16x16x32_bf16(ah, bh, acc0, 0, 0, 0);
        acc0 = __builtin_amdgcn_mfma_f32_16x16x32_bf16(ah, bl, acc0, 0, 0, 0);
        acc0 = __builtin_amdgcn_mfma_f32_16x16x32_bf16(al, bh, acc0, 0, 0, 0);
        bh = bh0[(size_t)KS * 64]; bl = bl0[(size_t)KS * 64];
        acc1 = __builtin_amdgcn_mfma_f32_16x16x32_bf16(ah, bh, acc1, 0, 0, 0);
        acc1 = __builtin_amdgcn_mfma_f32_16x16x32_bf16(ah, bl, acc1, 0, 0, 0);
        acc1 = __builtin_amdgcn_mfma_f32_16x16x32_bf16(al, bh, acc1, 0, 0, 0);
        bh = bh0[(size_t)KS * 128]; bl = bl0[(size_t)KS * 128];
        acc2 = __builtin_amdgcn_mfma_f32_16x16x32_bf16(ah, bh, acc2, 0, 0, 0);
        acc2 = __builtin_amdgcn_mfma_f32_16x16x32_bf16(ah, bl, acc2, 0, 0, 0);
        acc2 = __builtin_amdgcn_mfma_f32_16x16x32_bf16(al, bh, acc2, 0, 0, 0);
        bh = bh0[(size_t)KS * 192]; bl = bl0[(size_t)KS * 192];
        acc3 = __builtin_amdgcn_mfma_f32_16x16x32_bf16(ah, bh, acc3, 0, 0, 0);
        acc3 = __builtin_amdgcn_mfma_f32_16x16x32_bf16(ah, bl, acc3, 0, 0, 0);
        acc3 = __builtin_amdgcn_mfma_f32_16x16x32_bf16(al, bh, acc3, 0, 0, 0);
    }
    const int rbase = m0 + wv * 16 + ((lane >> 4) << 2);
    #pragma unroll
    for (int nt = 0; nt < 4; ++nt) {
        f32x4 a = (nt == 0) ? acc0 : (nt == 1) ? acc1 : (nt == 2) ? acc2 : acc3;
        int n = n0 + nt * 16 + (lane & 15);
        float bv = bias[n];
        #pragma unroll
        for (int r = 0; r < 4; ++r) {
            float v = a[r] + bv;
            if (RELU) v = fmaxf(v, 0.0f);
            C[(size_t)(rbase + r) * N + n] = v;
        }
    }
}

// ---------------- conv stack v5: conv1 8ch/thread + b128 stores; conv2/3 MFMA ----------------
__global__ __launch_bounds__(256) void conv_kernel(const float* __restrict__ x,
        const float* __restrict__ w1, const float* __restrict__ b1,
        const short* __restrict__ w2fh, const short* __restrict__ w2fl,
        const short* __restrict__ w3fh, const short* __restrict__ w3fl,
        short* __restrict__ outh, short* __restrict__ outl) {
    __shared__ float arena[15948];               // 63792 B
    float* s_img = arena;                        // [9804]
    short* sp    = (short*)(arena + 9804);
    short* o1ch  = sp;                           // [121][24]
    short* o1cl  = sp + 2904;
    short* o2ch  = sp + 5808;                    // [81][40]
    short* o2cl  = sp + 9048;
    const int t = threadIdx.x, lane = t & 63;
    const int wv = t >> 6;
    const int g  = lane >> 4;
    const size_t img = blockIdx.x;
    const bf16x8 zero8 = {0, 0, 0, 0, 0, 0, 0, 0};

    const float* xi = x + img * 9801;
    for (int i = t; i < 9801; i += 256) s_img[i] = xi[i] * (1.0f / 255.0f);
    __syncthreads();

    {   // conv1: thread = (position p = t&127, channel octet cg2 = t>>7); b128 stores
        const int cg2 = __builtin_amdgcn_readfirstlane(t >> 7);
        const int p = t & 127;
        if (p < 121) {
            int i = p / 11, j = p - i * 11;
            float acc[8];
            #pragma unroll
            for (int cc = 0; cc < 8; ++cc) acc[cc] = b1[cg2 * 8 + cc];
            for (int ky = 0; ky < 9; ++ky) {
                const float* irow = s_img + (i * 9 + ky) * 99 + j * 9;
                float row[9];
                #pragma unroll
                for (int kx = 0; kx < 9; ++kx) row[kx] = irow[kx];
                #pragma unroll
                for (int cc = 0; cc < 8; ++cc) {
                    const float* wr = w1 + (cg2 * 8 + cc) * 81 + ky * 9;
                    #pragma unroll
                    for (int kx = 0; kx < 9; ++kx) acc[cc] += wr[kx] * row[kx];
                }
            }
            bf16x8 vh, vl;
            #pragma unroll
            for (int cc = 0; cc < 8; ++cc) {
                float v = fmaxf(acc[cc], 0.0f);
                short h = f32_to_bf16_rne(v);
                vh[cc] = h;
                vl[cc] = f32_to_bf16_rne(v - bf16s_to_f32(h));
            }
            *(bf16x8*)&o1ch[p * 24 + cg2 * 8] = vh;
            *(bf16x8*)&o1cl[p * 24 + cg2 * 8] = vl;
        }
    }
    __syncthreads();

    {   // conv2 MFMA: k' = tap*16 + ic; fragment = ONE b128 from o1c
        const int ic0 = (g & 1) * 8;
        int toff2[5];
        #pragma unroll
        for (int ks = 0; ks < 5; ++ks) {
            int tap = 2 * ks + (g >> 1);
            if (tap > 8) tap = 8;
            toff2[ks] = (tap / 3) * 11 + (tap % 3);
        }
        #pragma unroll
        for (int i = 0; i < 3; ++i) {
            int tau = wv + 4 * i;
            int Mt = tau >> 1, Nt = tau & 1;
            int p = Mt * 16 + (lane & 15);
            int prow = (p / 9) * 11 + (p % 9);
            if (p >= 81) prow = 0;
            f32x4 acc = {0.f, 0.f, 0.f, 0.f};
            #pragma unroll
            for (int ks = 0; ks < 5; ++ks) {
                int ad = (prow + toff2[ks]) * 24 + ic0;
                bf16x8 ah = *(const bf16x8*)&o1ch[ad];
                bf16x8 al = *(const bf16x8*)&o1cl[ad];
                if (ks == 4 && g >= 2) { ah = zero8; al = zero8; }
                bf16x8 bh = ((const bf16x8*)w2fh)[(Nt * 5 + ks) * 64 + lane];
                bf16x8 bl = ((const bf16x8*)w2fl)[(Nt * 5 + ks) * 64 + lane];
                acc = __builtin_amdgcn_mfma_f32_16x16x32_bf16(ah, bh, acc, 0, 0, 0);
                acc = __builtin_amdgcn_mfma_f32_16x16x32_bf16(ah, bl, acc, 0, 0, 0);
                acc = __builtin_amdgcn_mfma_f32_16x16x32_bf16(al, bh, acc, 0, 0, 0);
            }
            int c = Nt * 16 + (lane & 15);
            #pragma unroll
            for (int r = 0; r < 4; ++r) {
                int pp = Mt * 16 + ((lane >> 4) << 2) + r;
                if (pp < 81) {
                    float v = fmaxf(acc[r], 0.0f);
                    short h = f32_to_bf16_rne(v);
                    o2ch[pp * 40 + c] = h;
                    o2cl[pp * 40 + c] = f32_to_bf16_rne(v - bf16s_to_f32(h));
                }
            }
        }
    }
    __syncthreads();

    {   // conv3 MFMA: k' = tap*32 + ic; K=288 exact
        short* ogh = outh + img * 1568;
        short* ogl = outl + img * 1568;
        #pragma unroll
        for (int i = 0; i < 2; ++i) {
            int tau = wv + 4 * i;
            int Mt = tau >> 1, Nt = tau & 1;
            int p = Mt * 16 + (lane & 15);
            int prow = (p / 7) * 9 + (p % 7);
            if (p >= 49) prow = 0;
            f32x4 acc = {0.f, 0.f, 0.f, 0.f};
            #pragma unroll
            for (int ks = 0; ks < 9; ++ks) {
                int toff = (ks / 3) * 9 + (ks % 3);
                int ad = (prow + toff) * 40 + g * 8;
                bf16x8 ah = *(const bf16x8*)&o2ch[ad];
                bf16x8 al = *(const bf16x8*)&o2cl[ad];
                bf16x8 bh = ((const bf16x8*)w3fh)[(Nt * 9 + ks) * 64 + lane];
                bf16x8 bl = ((const bf16x8*)w3fl)[(Nt * 9 + ks) * 64 + lane];
                acc = __builtin_amdgcn_mfma_f32_16x16x32_bf16(ah, bh, acc, 0, 0, 0);
                acc = __builtin_amdgcn_mfma_f32_16x16x32_bf16(ah, bl, acc, 0, 0, 0);
                acc = __builtin_amdgcn_mfma_f32_16x16x32_bf16(al, bh, acc, 0, 0, 0);
            }
            int c = Nt * 16 + (lane & 15);
            #pragma unroll
            for (int r = 0; r < 4; ++r) {
                int pp = Mt * 16 + ((lane >> 4) << 2) + r;
                if (pp < 49) {
                    float v = fmaxf(acc[r], 0.0f);
                    short h = f32_to_bf16_rne(v);
                    ogh[c * 49 + pp] = h;
                    ogl[c * 49 + pp] = f32_to_bf16_rne(v - bf16s_to_f32(h));
                }
            }
        }
    }
}

// ---------------- generic tiled fp32 GEMM (small cases) ----------------
template <bool RELU>
__global__ __launch_bounds__(64) void gemm64(const float* __restrict__ A, const float* __restrict__ W,
                                             const float* __restrict__ bias, float* __restrict__ C,
                                             int M, int N, int K) {
    __shared__ float At[32][68];
    __shared__ float Wt[32][68];
    const int m0 = blockIdx.x * 64, n0 = blockIdx.y * 64;
    const int t = threadIdx.x;
    const int tx = t & 7, ty = t >> 3;
    float acc[8][8] = {};
    for (int kc = 0; kc < K; kc += 32) {
        #pragma unroll
        for (int i = 0; i < 8; ++i) {
            int e = t + i * 64;
            int row = e >> 3, c4 = (e & 7) * 4;
            float4 v = *(const float4*)&A[(size_t)(m0 + row) * K + kc + c4];
            At[c4 + 0][row] = v.x; At[c4 + 1][row] = v.y; At[c4 + 2][row] = v.z; At[c4 + 3][row] = v.w;
            int n = n0 + row;
            float4 wv = make_float4(0.f, 0.f, 0.f, 0.f);
            if (n < N) wv = *(const float4*)&W[(size_t)n * K + kc + c4];
            Wt[c4 + 0][row] = wv.x; Wt[c4 + 1][row] = wv.y; Wt[c4 + 2][row] = wv.z; Wt[c4 + 3][row] = wv.w;
        }
        __syncthreads();
        #pragma unroll
        for (int kk = 0; kk < 32; ++kk) {
            float4 a0 = *(const float4*)&At[kk][ty * 8];
            float4 a1 = *(const float4*)&At[kk][ty * 8 + 4];
            float4 b0 = *(const float4*)&Wt[kk][tx * 8];
            float4 b1 = *(const float4*)&Wt[kk][tx * 8 + 4];
            float a[8] = {a0.x, a0.y, a0.z, a0.w, a1.x, a1.y, a1.z, a1.w};
            float b[8] = {b0.x, b0.y, b0.z, b0.w, b1.x, b1.y, b1.z, b1.w};
            #pragma unroll
            for (int i = 0; i < 8; ++i)
                #pragma unroll
                for (int j = 0; j < 8; ++j) acc[i][j] += a[i] * b[j];
        }
        __syncthreads();
    }
    #pragma unroll
    for (int i = 0; i < 8; ++i) {
        int m = m0 + ty * 8 + i;
        #pragma unroll
        for (int j = 0; j < 8; ++j) {
            int n = n0 + tx * 8 + j;
            if (n < N) {
                float v = acc[i][j] + bias[n];
                if (RELU) v = fmaxf(v, 0.0f);
                C[(size_t)m * N + n] = v;
            }
        }
    }
}

// ---------------- embedding ----------------
__global__ void embed_kernel(const int* __restrict__ lang, const float* __restrict__ emb,
                             float* __restrict__ out) {
    int g = blockIdx.x * 256 + threadIdx.x;
    if (g < TBTOT * 32) { int r = g >> 5, c = g & 31; out[g] = emb[lang[r] * 32 + c]; }
}

// ---------------- concat -> split bf16 hidden ----------------
__global__ void concat_kernel(const float* __restrict__ img_h, const float* __restrict__ lang_h,
                              short* __restrict__ outh, short* __restrict__ outl) {
    int r = blockIdx.x, c = threadIdx.x;
    float v = (c < 256) ? img_h[r * 256 + c] : lang_h[r * 32 + (c - 256)];
    short h = f32_to_bf16_rne(v);
    outh[r * 288 + c] = h;
    outl[r * 288 + c] = f32_to_bf16_rne(v - bf16s_to_f32(h));
}

// ---------------- ONE LSTM STEP, NB rows/block, XCD-aware 1-D grid ----------------
// grid = (H/16)*(BATCH/NB) linear. Bijective remap co-locates a j-tile's 4 b-group
// readers on one XCD: jt=(id&7)+8*(id>>5), bg=(id>>3)&3.
template <int H, int NB, bool PER_ENV>
__global__ __launch_bounds__(256) void lstm_step_kernel(
        const float* __restrict__ xw_s,
        const short* __restrict__ wf_hi,
        const short* __restrict__ wf_lo,
        const float* __restrict__ done_s,
        const short* __restrict__ hs_hi, const short* __restrict__ hs_lo,
        short* __restrict__ hd_hi, short* __restrict__ hd_lo,
        float* __restrict__ cbuf,
        float* __restrict__ hs_out) {
    constexpr int CK   = 8192 / NB;
    constexpr int SEGS = CK / 8;
    constexpr int NMT  = NB / 16;
    constexpr int NCH  = H / CK;
    constexpr int KSL  = CK / 32;
    __shared__ bf16x8 lsA[2][1024];
    __shared__ float  gbuf[4][NB][16];
    const int t    = threadIdx.x;
    const int lane = t & 63;
    const int q    = t >> 6;
    const int id   = blockIdx.x;
    const int jt   = (id & 7) + 8 * (id >> 5);
    const int bg   = (id >> 3) & 3;
    const int j0   = jt * 16;
    const int b0   = bg * NB;
    const int jl   = t & 15, bl = (t >> 4) & 15;
    const int jg   = j0 + jl;
    const int njt  = H >> 4, nks = H >> 5;

    const float m_step = PER_ENV ? 0.0f : (1.0f - done_s[0]);

    float xg[NMT][4], m_e[NMT];
    #pragma unroll
    for (int e = 0; e < NMT; ++e) {
        int bgl = b0 + bl + e * 16;
        const float* xr = xw_s + (size_t)bgl * (4 * H);
        #pragma unroll
        for (int g4 = 0; g4 < 4; ++g4) xg[e][g4] = xr[g4 * H + jg];
        m_e[e] = PER_ENV ? (1.0f - done_s[bgl]) : m_step;
    }

    f32x4 acc[NMT];
    #pragma unroll
    for (int m = 0; m < NMT; ++m) acc[m] = (f32x4){0.f, 0.f, 0.f, 0.f};
    const bf16x8* bfh = (const bf16x8*)wf_hi + (size_t)(q * njt + jt) * nks * 64;
    const bf16x8* bfl = (const bf16x8*)wf_lo + (size_t)(q * njt + jt) * nks * 64;
    const bf16x8 zero8 = {0, 0, 0, 0, 0, 0, 0, 0};

    for (int cch = 0; cch < NCH; ++cch) {
        const int k0 = cch * CK;
        #pragma unroll
        for (int i = 0; i < 4; ++i) {
            int idx = i * 256 + t;
            int row = idx / SEGS, seg = idx % SEGS;
            float m = PER_ENV ? (1.0f - done_s[b0 + row]) : m_step;
            int slot = seg * NB + ((row ^ seg) & (NB - 1));
            bf16x8 vh = *(const bf16x8*)&hs_hi[(size_t)(b0 + row) * H + k0 + seg * 8];
            bf16x8 vl = *(const bf16x8*)&hs_lo[(size_t)(b0 + row) * H + k0 + seg * 8];
            if (m == 0.0f) { vh = zero8; vl = zero8; }
            lsA[0][slot] = vh;
            lsA[1][slot] = vl;
        }
        __syncthreads();
        #pragma unroll
        for (int ksl = 0; ksl < KSL; ++ksl) {
            int ks = cch * KSL + ksl;
            bf16x8 b_hi = bfh[(size_t)ks * 64 + lane];
            bf16x8 b_lo = bfl[(size_t)ks * 64 + lane];
            int kgrp = ksl * 4 + (lane >> 4);
            #pragma unroll
            for (int mt = 0; mt < NMT; ++mt) {
                int row = mt * 16 + (lane & 15);
                int slot = kgrp * NB + ((row ^ kgrp) & (NB - 1));
                bf16x8 ah = lsA[0][slot];
                bf16x8 al = lsA[1][slot];
                acc[mt] = __builtin_amdgcn_mfma_f32_16x16x32_bf16(ah, b_hi, acc[mt], 0, 0, 0);
                acc[mt] = __builtin_amdgcn_mfma_f32_16x16x32_bf16(ah, b_lo, acc[mt], 0, 0, 0);
                acc[mt] = __builtin_amdgcn_mfma_f32_16x16x32_bf16(al, b_hi, acc[mt], 0, 0, 0);
            }
        }
        __syncthreads();
    }

    #pragma unroll
    for (int mt = 0; mt < NMT; ++mt)
        #pragma unroll
        for (int r = 0; r < 4; ++r)
            gbuf[q][mt * 16 + ((lane >> 4) << 2) + r][lane & 15] = acc[mt][r];
    __syncthreads();

    #pragma unroll
    for (int e = 0; e < NMT; ++e) {
        int b_loc = bl + e * 16;
        int bgl = b0 + b_loc;
        float m = m_e[e];
        float gi = gbuf[0][b_loc][jl] + xg[e][0];
        float gf = gbuf[1][b_loc][jl] + xg[e][1];
        float gg = gbuf[2][b_loc][jl] + xg[e][2];
        float go = gbuf[3][b_loc][jl] + xg[e][3];
        size_t ci = (size_t)bgl * H + jg;
        float cc = fast_sigm(gf) * (cbuf[ci] * m) + fast_sigm(gi) * fast_tanh(gg);
        float hh = fast_sigm(go) * fast_tanh(cc);
        cbuf[ci] = cc;
        hs_out[ci] = hh;
        short hhi = f32_to_bf16_rne(hh);
        short hlo = f32_to_bf16_rne(hh - bf16s_to_f32(hhi));
        hd_hi[ci] = hhi;
        hd_lo[ci] = hlo;
    }
}

extern "C" void kernel_launch(void* const* d_in, const int* in_sizes, int n_in,
                              void* d_out, int out_size, void* d_ws, size_t ws_size,
                              hipStream_t stream) {
    const float* x_img    = (const float*)d_in[0];
    const int*   x_lang   = (const int*)d_in[1];
    const float* done     = (const float*)d_in[2];
    const float* enc_h0   = (const float*)d_in[3];
    const float* enc_c0   = (const float*)d_in[4];
    const float* mem_h0   = (const float*)d_in[5];
    const float* mem_c0   = (const float*)d_in[6];
    const float* emb      = (const float*)d_in[7];
    const float* conv1_w  = (const float*)d_in[8];
    const float* conv1_b  = (const float*)d_in[9];
    const float* conv2_w  = (const float*)d_in[10];
    const float* conv2_b  = (const float*)d_in[11];
    const float* conv3_w  = (const float*)d_in[12];
    const float* conv3_b  = (const float*)d_in[13];
    const float* fc_w     = (const float*)d_in[14];
    const float* fc_b     = (const float*)d_in[15];
    const float* enc_Wih  = (const float*)d_in[16];
    const float* enc_Whh  = (const float*)d_in[17];
    const float* enc_bih  = (const float*)d_in[18];
    const float* enc_bhh  = (const float*)d_in[19];
    const float* lemb_w   = (const float*)d_in[20];
    const float* lemb_b   = (const float*)d_in[21];
    const float* mem_Wih  = (const float*)d_in[22];
    const float* mem_Whh  = (const float*)d_in[23];
    const float* mem_bih  = (const float*)d_in[24];
    const float* mem_bhh  = (const float*)d_in[25];
    const float* actor_w  = (const float*)d_in[26];
    const float* actor_b  = (const float*)d_in[27];
    const float* critic_w = (const float*)d_in[28];
    const float* critic_b = (const float*)d_in[29];

    float* ws = (float*)d_ws;
    short* convAh     = (short*)(ws + OFF_CONVH);
    short* convAl     = (short*)(ws + OFF_CONVL);
    short* mem_wf_hi  = (short*)(ws + OFF_MWFHI);
    short* mem_wf_lo  = (short*)(ws + OFF_MWFLO);
    short* enc_wf_hi  = (short*)(ws + OFF_EWFHI);
    short* enc_wf_lo  = (short*)(ws + OFF_EWFLO);
    short* hbm_hi     = (short*)(ws + OFF_HBMHI);
    short* hbm_lo     = (short*)(ws + OFF_HBMLO);
    short* hbe_hi     = (short*)(ws + OFF_HBEHI);
    short* hbe_lo     = (short*)(ws + OFF_HBELO);
    float* cbm        = ws + OFF_CBM;
    float* cbe        = ws + OFF_CBE;
    short* wihf_h     = (short*)(ws + OFF_WIHFH);
    short* wihf_l     = (short*)(ws + OFF_WIHFL);
    short* cw2h       = (short*)(ws + OFF_CW2H);
    short* cw2l       = (short*)(ws + OFF_CW2L);
    short* cw3h       = (short*)(ws + OFF_CW3H);
    short* cw3l       = (short*)(ws + OFF_CW3L);
    short* fcw_h      = (short*)(ws + OFF_FCWH);
    short* fcw_l      = (short*)(ws + OFF_FCWL);
    float* img_hidden = ws + OFF_IMGH;
    float* lang_in    = ws + OFF_LANGIN;
    float* enc_xW     = ws + OFF_ENCXW;
    float* enc_hs     = ws + OFF_ENCHS;
    float* lang_h     = ws + OFF_LANGH;
    short* hid_h      = (short*)(ws + OFF_HIDH);
    short* hid_l      = (short*)(ws + OFF_HIDL);
    float* mem_xW     = ws + OFF_MEMXW;
    float* mem_hs     = ws + OFF_MEMHS;
    float* enc_bc     = ws + OFF_ENCBC;
    float* mem_bc     = ws + OFF_MEMBC;
    float* head_w     = ws + OFF_HEADW;
    float* head_b     = ws + OFF_HEADB;

    prep_kernel<<<64, 256, 0, stream>>>(enc_bih, enc_bhh, mem_bih, mem_bhh,
                                        actor_w, actor_b, critic_w, critic_b,
                                        enc_bc, mem_bc, head_w, head_b);
    conv_frag_perm_kernel<<<20, 256, 0, stream>>>(conv2_w, cw2h, cw2l, 16, 5);
    conv_frag_perm_kernel<<<36, 256, 0, stream>>>(conv3_w, cw3h, cw3l, 32, 9);
    gemm_frag_kernel<<<1568, 256, 0, stream>>>(fc_w, fcw_h, fcw_l, 1568, 49, 16);
    conv_kernel<<<TBTOT, 256, 0, stream>>>(x_img, conv1_w, conv1_b,
                                           cw2h, cw2l, cw3h, cw3l, convAh, convAl);
    mfma_gemm<true><<<dim3(128, 4), 256, 0, stream>>>(convAh, convAl, fcw_h, fcw_l,
                                                      fc_b, img_hidden, 256, 1568, 49);
    // conv A region dead from here; LSTM fragments + state may now use it
    split_frag_kernel<<<65536, 256, 0, stream>>>(mem_Whh, mem_wf_hi, mem_wf_lo, 1024);
    split_frag_kernel<<<4096, 256, 0, stream>>>(enc_Whh, enc_wf_hi, enc_wf_lo, 256);
    gemm_frag_kernel<<<4608, 256, 0, stream>>>(mem_Wih, wihf_h, wihf_l, 288, 9, 256);
    init_state_kernel<<<128, 256, 0, stream>>>(enc_h0, enc_c0, hbe_hi, hbe_lo, cbe, BATCH * 256);
    init_state_kernel<<<512, 256, 0, stream>>>(mem_h0, mem_c0, hbm_hi, hbm_lo, cbm, BATCH * 1024);
    embed_kernel<<<1024, 256, 0, stream>>>(x_lang, emb, lang_in);
    gemm64<false><<<dim3(128, 16), 64, 0, stream>>>(lang_in, enc_Wih, enc_bc, enc_xW, TBTOT, 1024, 32);

    // ---- encoder scan (NB=32, grid 64 linear, XCD remap) ----
    {
        int cur = 0;
        for (int st = 0; st < T_STEPS; ++st) {
            lstm_step_kernel<256, 32, false><<<64, 256, 0, stream>>>(
                enc_xW + (size_t)st * BATCH * 1024, enc_wf_hi, enc_wf_lo, done + st,
                hbe_hi + (size_t)cur * (BATCH * 256), hbe_lo + (size_t)cur * (BATCH * 256),
                hbe_hi + (size_t)(cur ^ 1) * (BATCH * 256), hbe_lo + (size_t)(cur ^ 1) * (BATCH * 256),
                cbe, enc_hs + (size_t)st * BATCH * 256);
            cur ^= 1;
        }
    }
    gemm64<true><<<dim3(128, 1), 64, 0, stream>>>(enc_hs, lemb_w, lemb_b, lang_h, TBTOT, 32, 256);
    concat_kernel<<<TBTOT, 288, 0, stream>>>(img_hidden, lang_h, hid_h, hid_l);
    mfma_gemm<false><<<dim3(128, 64), 256, 0, stream>>>(hid_h, hid_l, wihf_h, wihf_l,
                                                        mem_bc, mem_xW, 4096, 288, 9);

    // ---- memory scan (NB=32, grid 256 linear, XCD remap) ----
    {
        int cur = 0;
        for (int st = 0; st < T_STEPS; ++st) {
            lstm_step_kernel<1024, 32, true><<<256, 256, 0, stream>>>(
                mem_xW + (size_t)st * BATCH * 4096, mem_wf_hi, mem_wf_lo, done + (size_t)st * BATCH,
                hbm_hi + (size_t)cur * (BATCH * 1024), hbm_lo + (size_t)cur * (BATCH * 1024),
                hbm_hi + (size_t)(cur ^ 1) * (BATCH * 1024), hbm_lo + (size_t)(cur ^ 1) * (BATCH * 1024),
                cbm, mem_hs + (size_t)st * BATCH * 1024);
            cur ^= 1;
        }
    }
    gemm64<false><<<dim3(128, 1), 64, 0, stream>>>(mem_hs, head_w, head_b, (float*)d_out, TBTOT, 16, 1024);
}

// Round 19
// 1666.716 us; speedup vs baseline: 1.0344x; 1.0344x over previous
//
#include <hip/hip_runtime.h>
#include <math.h>

#define T_STEPS 64
#define BATCH   128
#define TBTOT   8192

typedef __attribute__((ext_vector_type(8))) short bf16x8;
typedef __attribute__((ext_vector_type(4))) float f32x4;

// ---------------- workspace layout (float offsets) ----------------
// NOTE region lifetimes: [0,12845056) holds convAh/convAl during conv+fc, then is
// reused for LSTM fragments + state. State init MUST run after the fc GEMM.
static const size_t OFF_CONVH  = 0;              // [8192*1568] bf16 hi
static const size_t OFF_CONVL  = 6422528;        // [8192*1568] bf16 lo
static const size_t OFF_MWFHI  = 0;              // [4096*1024] bf16 (phase 2)
static const size_t OFF_MWFLO  = 2097152;
static const size_t OFF_EWFHI  = 4194304;        // [1024*256] bf16
static const size_t OFF_EWFLO  = 4325376;
static const size_t OFF_HBMHI  = 4456448;        // [2][128][1024] bf16
static const size_t OFF_HBMLO  = 4587520;
static const size_t OFF_HBEHI  = 4718592;        // [2][128][256] bf16
static const size_t OFF_HBELO  = 4734976;
static const size_t OFF_CBM    = 4767744;        // [128][1024] f32
static const size_t OFF_CBE    = 4898816;        // [128][256] f32
static const size_t OFF_WIHFH  = 4931584;        // [4096*288] bf16
static const size_t OFF_WIHFL  = 5521408;
static const size_t OFF_IMGH   = 12845056;       // [8192][256]
static const size_t OFF_LANGIN = 14942208;       // [8192][32]
static const size_t OFF_ENCXW  = 15204352;       // [8192][1024]
static const size_t OFF_ENCHS  = 23592960;       // [8192][256]
static const size_t OFF_LANGH  = 25690112;       // [8192][32]
static const size_t OFF_HIDH   = 25952256;       // [8192*288] bf16 hi
static const size_t OFF_HIDL   = 27131904;       // [8192*288] bf16 lo
static const size_t OFF_MEMXW  = 28311552;       // [8192][4096]
static const size_t OFF_CW2H   = 28311552;       // 5120 shorts
static const size_t OFF_CW2L   = 28314112;
static const size_t OFF_CW3H   = 28316672;       // 9216 shorts
static const size_t OFF_CW3L   = 28321280;
static const size_t OFF_FCWH   = 28325888;       // [256*1568] bf16
static const size_t OFF_FCWL   = 28526592;
static const size_t OFF_MEMHS  = 61865984;       // [8192][1024]
static const size_t OFF_ENCBC  = 70582272;       // [1024]
static const size_t OFF_MEMBC  = 70583296;       // [4096]
static const size_t OFF_HEADW  = 70587392;       // [16][1024]
static const size_t OFF_HEADB  = 70603776;       // [16]

__device__ __forceinline__ float fast_sigm(float x) { return 1.0f / (1.0f + __expf(-x)); }
__device__ __forceinline__ float fast_tanh(float x) { return 2.0f / (1.0f + __expf(-2.0f * x)) - 1.0f; }

__device__ __forceinline__ short f32_to_bf16_rne(float x) {
    unsigned u = __float_as_uint(x);
    unsigned r = (u + 0x7fffu + ((u >> 16) & 1u)) >> 16;
    return (short)r;
}
__device__ __forceinline__ float bf16s_to_f32(short s) {
    return __uint_as_float(((unsigned)(unsigned short)s) << 16);
}

// ---------------- prep ----------------
__global__ void prep_kernel(const float* __restrict__ enc_bih, const float* __restrict__ enc_bhh,
                            const float* __restrict__ mem_bih, const float* __restrict__ mem_bhh,
                            const float* __restrict__ actor_w, const float* __restrict__ actor_b,
                            const float* __restrict__ critic_w, const float* __restrict__ critic_b,
                            float* __restrict__ enc_bc, float* __restrict__ mem_bc,
                            float* __restrict__ head_w, float* __restrict__ head_b) {
    int g = blockIdx.x * 256 + threadIdx.x;
    if (g < 1024)  enc_bc[g] = enc_bih[g] + enc_bhh[g];
    if (g < 4096)  mem_bc[g] = mem_bih[g] + mem_bhh[g];
    if (g < 16384) { int j = g >> 10, k = g & 1023; head_w[g] = (j < 15) ? actor_w[j * 1024 + k] : critic_w[k]; }
    if (g < 16)    head_b[g] = (g < 15) ? actor_b[g] : critic_b[0];
}

// ---------------- init LSTM state (runs AFTER fc GEMM frees the region) ----------------
__global__ void init_state_kernel(const float* __restrict__ h0, const float* __restrict__ c0,
                                  short* __restrict__ hhi, short* __restrict__ hlo,
                                  float* __restrict__ cb, int n) {
    int g = blockIdx.x * 256 + threadIdx.x;
    if (g < n) {
        float v = h0[g];
        short a = f32_to_bf16_rne(v);
        hhi[g] = a;
        hlo[g] = f32_to_bf16_rne(v - bf16s_to_f32(a));
        cb[g] = c0[g];
    }
}

// ---------------- split Whh into MFMA-fragment-ordered bf16 hi/lo ----------------
__global__ void split_frag_kernel(const float* __restrict__ W, short* __restrict__ hi,
                                  short* __restrict__ lo, int H) {
    size_t f = (size_t)blockIdx.x * 256 + threadIdx.x;
    size_t total = (size_t)4 * H * H;
    if (f >= total) return;
    int e    = (int)(f & 7);
    int lane = (int)((f >> 3) & 63);
    size_t rest = f >> 9;
    int nks = H >> 5;
    int ks  = (int)(rest % nks);
    int qjt = (int)(rest / nks);
    int njt = H >> 4;
    int qq = qjt / njt, jt = qjt - qq * njt;
    int n = qq * H + jt * 16 + (lane & 15);
    int k = ks * 32 + (lane >> 4) * 8 + e;
    float w = W[(size_t)n * H + k];
    short a = f32_to_bf16_rne(w);
    short b = f32_to_bf16_rne(w - bf16s_to_f32(a));
    hi[f] = a; lo[f] = b;
}

// ---------------- generic GEMM weight frags (row-major K) ----------------
__global__ void gemm_frag_kernel(const float* __restrict__ W, short* __restrict__ hi,
                                 short* __restrict__ lo, int Kv, int nks, int ntot) {
    int f = blockIdx.x * 256 + threadIdx.x;
    int total = ntot * nks * 512;
    if (f >= total) return;
    int e    = f & 7;
    int lane = (f >> 3) & 63;
    int rest = f >> 9;
    int ks   = rest % nks;
    int nt   = rest / nks;
    int n = nt * 16 + (lane & 15);
    int k = ks * 32 + (lane >> 4) * 8 + e;
    float w = (k < Kv) ? W[(size_t)n * Kv + k] : 0.0f;
    short a = f32_to_bf16_rne(w);
    short b = f32_to_bf16_rne(w - bf16s_to_f32(a));
    hi[f] = a; lo[f] = b;
}

// ---------------- conv weight frags, TAP-MAJOR permuted K: k' = tap*ICN + ic ----------------
__global__ void conv_frag_perm_kernel(const float* __restrict__ W, short* __restrict__ hi,
                                      short* __restrict__ lo, int ICN, int nks) {
    int f = blockIdx.x * 256 + threadIdx.x;
    int total = 2 * nks * 512;
    if (f >= total) return;
    int e    = f & 7;
    int lane = (f >> 3) & 63;
    int rest = f >> 9;
    int ks   = rest % nks;
    int nt   = rest / nks;
    int n  = nt * 16 + (lane & 15);
    int kp = ks * 32 + (lane >> 4) * 8 + e;
    int Kv = ICN * 9;
    float w = 0.0f;
    if (kp < Kv) {
        int tap = kp / ICN, ic = kp % ICN;
        w = W[(size_t)n * Kv + ic * 9 + tap];
    }
    short a = f32_to_bf16_rne(w);
    short b = f32_to_bf16_rne(w - bf16s_to_f32(a));
    hi[f] = a; lo[f] = b;
}

// ---------------- MFMA split-bf16 GEMM, 64x64 tile ----------------
template <bool RELU>
__global__ __launch_bounds__(256) void mfma_gemm(
        const short* __restrict__ Ah, const short* __restrict__ Al,
        const short* __restrict__ Wfh, const short* __restrict__ Wfl,
        const float* __restrict__ bias, float* __restrict__ C,
        int N, int K, int KS) {
    const int t = threadIdx.x, lane = t & 63, wv = t >> 6;
    const int m0 = blockIdx.x * 64, n0 = blockIdx.y * 64;
    const int pr = m0 + wv * 16 + (lane & 15);
    const size_t abase = (size_t)pr * K + ((lane >> 4) << 3);
    const int ntg0 = n0 >> 4;
    f32x4 acc0 = {0.f,0.f,0.f,0.f}, acc1 = {0.f,0.f,0.f,0.f};
    f32x4 acc2 = {0.f,0.f,0.f,0.f}, acc3 = {0.f,0.f,0.f,0.f};
    for (int ks = 0; ks < KS; ++ks) {
        bf16x8 ah = *(const bf16x8*)&Ah[abase + (size_t)ks * 32];
        bf16x8 al = *(const bf16x8*)&Al[abase + (size_t)ks * 32];
        const bf16x8* bh0 = (const bf16x8*)Wfh + ((size_t)ntg0 * KS + ks) * 64 + lane;
        const bf16x8* bl0 = (const bf16x8*)Wfl + ((size_t)ntg0 * KS + ks) * 64 + lane;
        bf16x8 bh, bl;
        bh = bh0[0];            bl = bl0[0];
        acc0 = __builtin_amdgcn_mfma_f32_16x16x32_bf16(ah, bh, acc0, 0, 0, 0);
        acc0 = __builtin_amdgcn_mfma_f32_16x16x32_bf16(ah, bl, acc0, 0, 0, 0);
        acc0 = __builtin_amdgcn_mfma_f32_16x16x32_bf16(al, bh, acc0, 0, 0, 0);
        bh = bh0[(size_t)KS * 64]; bl = bl0[(size_t)KS * 64];
        acc1 = __builtin_amdgcn_mfma_f32_16x16x32_bf16(ah, bh, acc1, 0, 0, 0);
        acc1 = __builtin_amdgcn_mfma_f32_16x16x32_bf16(ah, bl, acc1, 0, 0, 0);
        acc1 = __builtin_amdgcn_mfma_f32_16x16x32_bf16(al, bh, acc1, 0, 0, 0);
        bh = bh0[(size_t)KS * 128]; bl = bl0[(size_t)KS * 128];
        acc2 = __builtin_amdgcn_mfma_f32_16x16x32_bf16(ah, bh, acc2, 0, 0, 0);
        acc2 = __builtin_amdgcn_mfma_f32_16x16x32_bf16(ah, bl, acc2, 0, 0, 0);
        acc2 = __builtin_amdgcn_mfma_f32_16x16x32_bf16(al, bh, acc2, 0, 0, 0);
        bh = bh0[(size_t)KS * 192]; bl = bl0[(size_t)KS * 192];
        acc3 = __builtin_amdgcn_mfma_f32_16x16x32_bf16(ah, bh, acc3, 0, 0, 0);
        acc3 = __builtin_amdgcn_mfma_f32_16x16x32_bf16(ah, bl, acc3, 0, 0, 0);
        acc3 = __builtin_amdgcn_mfma_f32_16x16x32_bf16(al, bh, acc3, 0, 0, 0);
    }
    const int rbase = m0 + wv * 16 + ((lane >> 4) << 2);
    #pragma unroll
    for (int nt = 0; nt < 4; ++nt) {
        f32x4 a = (nt == 0) ? acc0 : (nt == 1) ? acc1 : (nt == 2) ? acc2 : acc3;
        int n = n0 + nt * 16 + (lane & 15);
        float bv = bias[n];
        #pragma unroll
        for (int r = 0; r < 4; ++r) {
            float v = a[r] + bv;
            if (RELU) v = fmaxf(v, 0.0f);
            C[(size_t)(rbase + r) * N + n] = v;
        }
    }
}

// ---------------- conv stack v5: conv1 8ch/thread + b128 stores; conv2/3 MFMA ----------------
__global__ __launch_bounds__(256) void conv_kernel(const float* __restrict__ x,
        const float* __restrict__ w1, const float* __restrict__ b1,
        const short* __restrict__ w2fh, const short* __restrict__ w2fl,
        const short* __restrict__ w3fh, const short* __restrict__ w3fl,
        short* __restrict__ outh, short* __restrict__ outl) {
    __shared__ float arena[15948];               // 63792 B
    float* s_img = arena;                        // [9804]
    short* sp    = (short*)(arena + 9804);
    short* o1ch  = sp;                           // [121][24]
    short* o1cl  = sp + 2904;
    short* o2ch  = sp + 5808;                    // [81][40]
    short* o2cl  = sp + 9048;
    const int t = threadIdx.x, lane = t & 63;
    const int wv = t >> 6;
    const int g  = lane >> 4;
    const size_t img = blockIdx.x;
    const bf16x8 zero8 = {0, 0, 0, 0, 0, 0, 0, 0};

    const float* xi = x + img * 9801;
    for (int i = t; i < 9801; i += 256) s_img[i] = xi[i] * (1.0f / 255.0f);
    __syncthreads();

    {   // conv1: thread = (position p = t&127, channel octet cg2 = t>>7); b128 stores
        const int cg2 = __builtin_amdgcn_readfirstlane(t >> 7);
        const int p = t & 127;
        if (p < 121) {
            int i = p / 11, j = p - i * 11;
            float acc[8];
            #pragma unroll
            for (int cc = 0; cc < 8; ++cc) acc[cc] = b1[cg2 * 8 + cc];
            for (int ky = 0; ky < 9; ++ky) {
                const float* irow = s_img + (i * 9 + ky) * 99 + j * 9;
                float row[9];
                #pragma unroll
                for (int kx = 0; kx < 9; ++kx) row[kx] = irow[kx];
                #pragma unroll
                for (int cc = 0; cc < 8; ++cc) {
                    const float* wr = w1 + (cg2 * 8 + cc) * 81 + ky * 9;
                    #pragma unroll
                    for (int kx = 0; kx < 9; ++kx) acc[cc] += wr[kx] * row[kx];
                }
            }
            bf16x8 vh, vl;
            #pragma unroll
            for (int cc = 0; cc < 8; ++cc) {
                float v = fmaxf(acc[cc], 0.0f);
                short h = f32_to_bf16_rne(v);
                vh[cc] = h;
                vl[cc] = f32_to_bf16_rne(v - bf16s_to_f32(h));
            }
            *(bf16x8*)&o1ch[p * 24 + cg2 * 8] = vh;
            *(bf16x8*)&o1cl[p * 24 + cg2 * 8] = vl;
        }
    }
    __syncthreads();

    {   // conv2 MFMA: k' = tap*16 + ic; fragment = ONE b128 from o1c
        const int ic0 = (g & 1) * 8;
        int toff2[5];
        #pragma unroll
        for (int ks = 0; ks < 5; ++ks) {
            int tap = 2 * ks + (g >> 1);
            if (tap > 8) tap = 8;
            toff2[ks] = (tap / 3) * 11 + (tap % 3);
        }
        #pragma unroll
        for (int i = 0; i < 3; ++i) {
            int tau = wv + 4 * i;
            int Mt = tau >> 1, Nt = tau & 1;
            int p = Mt * 16 + (lane & 15);
            int prow = (p / 9) * 11 + (p % 9);
            if (p >= 81) prow = 0;
            f32x4 acc = {0.f, 0.f, 0.f, 0.f};
            #pragma unroll
            for (int ks = 0; ks < 5; ++ks) {
                int ad = (prow + toff2[ks]) * 24 + ic0;
                bf16x8 ah = *(const bf16x8*)&o1ch[ad];
                bf16x8 al = *(const bf16x8*)&o1cl[ad];
                if (ks == 4 && g >= 2) { ah = zero8; al = zero8; }
                bf16x8 bh = ((const bf16x8*)w2fh)[(Nt * 5 + ks) * 64 + lane];
                bf16x8 bl = ((const bf16x8*)w2fl)[(Nt * 5 + ks) * 64 + lane];
                acc = __builtin_amdgcn_mfma_f32_16x16x32_bf16(ah, bh, acc, 0, 0, 0);
                acc = __builtin_amdgcn_mfma_f32_16x16x32_bf16(ah, bl, acc, 0, 0, 0);
                acc = __builtin_amdgcn_mfma_f32_16x16x32_bf16(al, bh, acc, 0, 0, 0);
            }
            int c = Nt * 16 + (lane & 15);
            #pragma unroll
            for (int r = 0; r < 4; ++r) {
                int pp = Mt * 16 + ((lane >> 4) << 2) + r;
                if (pp < 81) {
                    float v = fmaxf(acc[r], 0.0f);
                    short h = f32_to_bf16_rne(v);
                    o2ch[pp * 40 + c] = h;
                    o2cl[pp * 40 + c] = f32_to_bf16_rne(v - bf16s_to_f32(h));
                }
            }
        }
    }
    __syncthreads();

    {   // conv3 MFMA: k' = tap*32 + ic; K=288 exact
        short* ogh = outh + img * 1568;
        short* ogl = outl + img * 1568;
        #pragma unroll
        for (int i = 0; i < 2; ++i) {
            int tau = wv + 4 * i;
            int Mt = tau >> 1, Nt = tau & 1;
            int p = Mt * 16 + (lane & 15);
            int prow = (p / 7) * 9 + (p % 7);
            if (p >= 49) prow = 0;
            f32x4 acc = {0.f, 0.f, 0.f, 0.f};
            #pragma unroll
            for (int ks = 0; ks < 9; ++ks) {
                int toff = (ks / 3) * 9 + (ks % 3);
                int ad = (prow + toff) * 40 + g * 8;
                bf16x8 ah = *(const bf16x8*)&o2ch[ad];
                bf16x8 al = *(const bf16x8*)&o2cl[ad];
                bf16x8 bh = ((const bf16x8*)w3fh)[(Nt * 9 + ks) * 64 + lane];
                bf16x8 bl = ((const bf16x8*)w3fl)[(Nt * 9 + ks) * 64 + lane];
                acc = __builtin_amdgcn_mfma_f32_16x16x32_bf16(ah, bh, acc, 0, 0, 0);
                acc = __builtin_amdgcn_mfma_f32_16x16x32_bf16(ah, bl, acc, 0, 0, 0);
                acc = __builtin_amdgcn_mfma_f32_16x16x32_bf16(al, bh, acc, 0, 0, 0);
            }
            int c = Nt * 16 + (lane & 15);
            #pragma unroll
            for (int r = 0; r < 4; ++r) {
                int pp = Mt * 16 + ((lane >> 4) << 2) + r;
                if (pp < 49) {
                    float v = fmaxf(acc[r], 0.0f);
                    short h = f32_to_bf16_rne(v);
                    ogh[c * 49 + pp] = h;
                    ogl[c * 49 + pp] = f32_to_bf16_rne(v - bf16s_to_f32(h));
                }
            }
        }
    }
}

// ---------------- generic tiled fp32 GEMM (small cases) ----------------
template <bool RELU>
__global__ __launch_bounds__(64) void gemm64(const float* __restrict__ A, const float* __restrict__ W,
                                             const float* __restrict__ bias, float* __restrict__ C,
                                             int M, int N, int K) {
    __shared__ float At[32][68];
    __shared__ float Wt[32][68];
    const int m0 = blockIdx.x * 64, n0 = blockIdx.y * 64;
    const int t = threadIdx.x;
    const int tx = t & 7, ty = t >> 3;
    float acc[8][8] = {};
    for (int kc = 0; kc < K; kc += 32) {
        #pragma unroll
        for (int i = 0; i < 8; ++i) {
            int e = t + i * 64;
            int row = e >> 3, c4 = (e & 7) * 4;
            float4 v = *(const float4*)&A[(size_t)(m0 + row) * K + kc + c4];
            At[c4 + 0][row] = v.x; At[c4 + 1][row] = v.y; At[c4 + 2][row] = v.z; At[c4 + 3][row] = v.w;
            int n = n0 + row;
            float4 wv = make_float4(0.f, 0.f, 0.f, 0.f);
            if (n < N) wv = *(const float4*)&W[(size_t)n * K + kc + c4];
            Wt[c4 + 0][row] = wv.x; Wt[c4 + 1][row] = wv.y; Wt[c4 + 2][row] = wv.z; Wt[c4 + 3][row] = wv.w;
        }
        __syncthreads();
        #pragma unroll
        for (int kk = 0; kk < 32; ++kk) {
            float4 a0 = *(const float4*)&At[kk][ty * 8];
            float4 a1 = *(const float4*)&At[kk][ty * 8 + 4];
            float4 b0 = *(const float4*)&Wt[kk][tx * 8];
            float4 b1 = *(const float4*)&Wt[kk][tx * 8 + 4];
            float a[8] = {a0.x, a0.y, a0.z, a0.w, a1.x, a1.y, a1.z, a1.w};
            float b[8] = {b0.x, b0.y, b0.z, b0.w, b1.x, b1.y, b1.z, b1.w};
            #pragma unroll
            for (int i = 0; i < 8; ++i)
                #pragma unroll
                for (int j = 0; j < 8; ++j) acc[i][j] += a[i] * b[j];
        }
        __syncthreads();
    }
    #pragma unroll
    for (int i = 0; i < 8; ++i) {
        int m = m0 + ty * 8 + i;
        #pragma unroll
        for (int j = 0; j < 8; ++j) {
            int n = n0 + tx * 8 + j;
            if (n < N) {
                float v = acc[i][j] + bias[n];
                if (RELU) v = fmaxf(v, 0.0f);
                C[(size_t)m * N + n] = v;
            }
        }
    }
}

// ---------------- embedding ----------------
__global__ void embed_kernel(const int* __restrict__ lang, const float* __restrict__ emb,
                             float* __restrict__ out) {
    int g = blockIdx.x * 256 + threadIdx.x;
    if (g < TBTOT * 32) { int r = g >> 5, c = g & 31; out[g] = emb[lang[r] * 32 + c]; }
}

// ---------------- concat -> split bf16 hidden ----------------
__global__ void concat_kernel(const float* __restrict__ img_h, const float* __restrict__ lang_h,
                              short* __restrict__ outh, short* __restrict__ outl) {
    int r = blockIdx.x, c = threadIdx.x;
    float v = (c < 256) ? img_h[r * 256 + c] : lang_h[r * 32 + (c - 256)];
    short h = f32_to_bf16_rne(v);
    outh[r * 288 + c] = h;
    outl[r * 288 + c] = f32_to_bf16_rne(v - bf16s_to_f32(h));
}

// ---------------- ONE LSTM STEP, NB batch rows per block (dim3 grid) ----------------
template <int H, int NB, bool PER_ENV>
__global__ __launch_bounds__(256) void lstm_step_kernel(
        const float* __restrict__ xw_s,    // [B][4H] for this step
        const short* __restrict__ wf_hi,
        const short* __restrict__ wf_lo,
        const float* __restrict__ done_s,  // PER_ENV ? [B] : [1] scalar
        const short* __restrict__ hs_hi, const short* __restrict__ hs_lo,
        short* __restrict__ hd_hi, short* __restrict__ hd_lo,
        float* __restrict__ cbuf,
        float* __restrict__ hs_out) {
    constexpr int CK   = 8192 / NB;
    constexpr int SEGS = CK / 8;
    constexpr int NMT  = NB / 16;
    constexpr int NCH  = H / CK;
    constexpr int KSL  = CK / 32;
    __shared__ bf16x8 lsA[2][1024];
    __shared__ float  gbuf[4][NB][16];
    const int t    = threadIdx.x;
    const int lane = t & 63;
    const int q    = t >> 6;
    const int jt   = blockIdx.x;
    const int j0   = jt * 16;
    const int b0   = blockIdx.y * NB;
    const int jl   = t & 15, bl = (t >> 4) & 15;
    const int jg   = j0 + jl;
    const int njt  = H >> 4, nks = H >> 5;

    const float m_step = PER_ENV ? 0.0f : (1.0f - done_s[0]);

    float xg[NMT][4], m_e[NMT];
    #pragma unroll
    for (int e = 0; e < NMT; ++e) {
        int bgl = b0 + bl + e * 16;
        const float* xr = xw_s + (size_t)bgl * (4 * H);
        #pragma unroll
        for (int g4 = 0; g4 < 4; ++g4) xg[e][g4] = xr[g4 * H + jg];
        m_e[e] = PER_ENV ? (1.0f - done_s[bgl]) : m_step;
    }

    f32x4 acc[NMT];
    #pragma unroll
    for (int m = 0; m < NMT; ++m) acc[m] = (f32x4){0.f, 0.f, 0.f, 0.f};
    const bf16x8* bfh = (const bf16x8*)wf_hi + (size_t)(q * njt + jt) * nks * 64;
    const bf16x8* bfl = (const bf16x8*)wf_lo + (size_t)(q * njt + jt) * nks * 64;
    const bf16x8 zero8 = {0, 0, 0, 0, 0, 0, 0, 0};

    for (int cch = 0; cch < NCH; ++cch) {
        const int k0 = cch * CK;
        #pragma unroll
        for (int i = 0; i < 4; ++i) {
            int idx = i * 256 + t;
            int row = idx / SEGS, seg = idx % SEGS;
            float m = PER_ENV ? (1.0f - done_s[b0 + row]) : m_step;
            int slot = seg * NB + ((row ^ seg) & (NB - 1));
            bf16x8 vh = *(const bf16x8*)&hs_hi[(size_t)(b0 + row) * H + k0 + seg * 8];
            bf16x8 vl = *(const bf16x8*)&hs_lo[(size_t)(b0 + row) * H + k0 + seg * 8];
            if (m == 0.0f) { vh = zero8; vl = zero8; }
            lsA[0][slot] = vh;
            lsA[1][slot] = vl;
        }
        __syncthreads();
        #pragma unroll
        for (int ksl = 0; ksl < KSL; ++ksl) {
            int ks = cch * KSL + ksl;
            bf16x8 b_hi = bfh[(size_t)ks * 64 + lane];
            bf16x8 b_lo = bfl[(size_t)ks * 64 + lane];
            int kgrp = ksl * 4 + (lane >> 4);
            #pragma unroll
            for (int mt = 0; mt < NMT; ++mt) {
                int row = mt * 16 + (lane & 15);
                int slot = kgrp * NB + ((row ^ kgrp) & (NB - 1));
                bf16x8 ah = lsA[0][slot];
                bf16x8 al = lsA[1][slot];
                acc[mt] = __builtin_amdgcn_mfma_f32_16x16x32_bf16(ah, b_hi, acc[mt], 0, 0, 0);
                acc[mt] = __builtin_amdgcn_mfma_f32_16x16x32_bf16(ah, b_lo, acc[mt], 0, 0, 0);
                acc[mt] = __builtin_amdgcn_mfma_f32_16x16x32_bf16(al, b_hi, acc[mt], 0, 0, 0);
            }
        }
        __syncthreads();
    }

    // gate partial write (C/D layout: col=lane&15, row=(lane>>4)*4+r)
    #pragma unroll
    for (int mt = 0; mt < NMT; ++mt)
        #pragma unroll
        for (int r = 0; r < 4; ++r)
            gbuf[q][mt * 16 + ((lane >> 4) << 2) + r][lane & 15] = acc[mt][r];
    __syncthreads();

    #pragma unroll
    for (int e = 0; e < NMT; ++e) {
        int b_loc = bl + e * 16;
        int bgl = b0 + b_loc;
        float m = m_e[e];
        float gi = gbuf[0][b_loc][jl] + xg[e][0];
        float gf = gbuf[1][b_loc][jl] + xg[e][1];
        float gg = gbuf[2][b_loc][jl] + xg[e][2];
        float go = gbuf[3][b_loc][jl] + xg[e][3];
        size_t ci = (size_t)bgl * H + jg;
        float cc = fast_sigm(gf) * (cbuf[ci] * m) + fast_sigm(gi) * fast_tanh(gg);
        float hh = fast_sigm(go) * fast_tanh(cc);
        cbuf[ci] = cc;
        hs_out[ci] = hh;
        short hhi = f32_to_bf16_rne(hh);
        short hlo = f32_to_bf16_rne(hh - bf16s_to_f32(hhi));
        hd_hi[ci] = hhi;
        hd_lo[ci] = hlo;
    }
}

extern "C" void kernel_launch(void* const* d_in, const int* in_sizes, int n_in,
                              void* d_out, int out_size, void* d_ws, size_t ws_size,
                              hipStream_t stream) {
    const float* x_img    = (const float*)d_in[0];
    const int*   x_lang   = (const int*)d_in[1];
    const float* done     = (const float*)d_in[2];
    const float* enc_h0   = (const float*)d_in[3];
    const float* enc_c0   = (const float*)d_in[4];
    const float* mem_h0   = (const float*)d_in[5];
    const float* mem_c0   = (const float*)d_in[6];
    const float* emb      = (const float*)d_in[7];
    const float* conv1_w  = (const float*)d_in[8];
    const float* conv1_b  = (const float*)d_in[9];
    const float* conv2_w  = (const float*)d_in[10];
    const float* conv2_b  = (const float*)d_in[11];
    const float* conv3_w  = (const float*)d_in[12];
    const float* conv3_b  = (const float*)d_in[13];
    const float* fc_w     = (const float*)d_in[14];
    const float* fc_b     = (const float*)d_in[15];
    const float* enc_Wih  = (const float*)d_in[16];
    const float* enc_Whh  = (const float*)d_in[17];
    const float* enc_bih  = (const float*)d_in[18];
    const float* enc_bhh  = (const float*)d_in[19];
    const float* lemb_w   = (const float*)d_in[20];
    const float* lemb_b   = (const float*)d_in[21];
    const float* mem_Wih  = (const float*)d_in[22];
    const float* mem_Whh  = (const float*)d_in[23];
    const float* mem_bih  = (const float*)d_in[24];
    const float* mem_bhh  = (const float*)d_in[25];
    const float* actor_w  = (const float*)d_in[26];
    const float* actor_b  = (const float*)d_in[27];
    const float* critic_w = (const float*)d_in[28];
    const float* critic_b = (const float*)d_in[29];

    float* ws = (float*)d_ws;
    short* convAh     = (short*)(ws + OFF_CONVH);
    short* convAl     = (short*)(ws + OFF_CONVL);
    short* mem_wf_hi  = (short*)(ws + OFF_MWFHI);
    short* mem_wf_lo  = (short*)(ws + OFF_MWFLO);
    short* enc_wf_hi  = (short*)(ws + OFF_EWFHI);
    short* enc_wf_lo  = (short*)(ws + OFF_EWFLO);
    short* hbm_hi     = (short*)(ws + OFF_HBMHI);
    short* hbm_lo     = (short*)(ws + OFF_HBMLO);
    short* hbe_hi     = (short*)(ws + OFF_HBEHI);
    short* hbe_lo     = (short*)(ws + OFF_HBELO);
    float* cbm        = ws + OFF_CBM;
    float* cbe        = ws + OFF_CBE;
    short* wihf_h     = (short*)(ws + OFF_WIHFH);
    short* wihf_l     = (short*)(ws + OFF_WIHFL);
    short* cw2h       = (short*)(ws + OFF_CW2H);
    short* cw2l       = (short*)(ws + OFF_CW2L);
    short* cw3h       = (short*)(ws + OFF_CW3H);
    short* cw3l       = (short*)(ws + OFF_CW3L);
    short* fcw_h      = (short*)(ws + OFF_FCWH);
    short* fcw_l      = (short*)(ws + OFF_FCWL);
    float* img_hidden = ws + OFF_IMGH;
    float* lang_in    = ws + OFF_LANGIN;
    float* enc_xW     = ws + OFF_ENCXW;
    float* enc_hs     = ws + OFF_ENCHS;
    float* lang_h     = ws + OFF_LANGH;
    short* hid_h      = (short*)(ws + OFF_HIDH);
    short* hid_l      = (short*)(ws + OFF_HIDL);
    float* mem_xW     = ws + OFF_MEMXW;
    float* mem_hs     = ws + OFF_MEMHS;
    float* enc_bc     = ws + OFF_ENCBC;
    float* mem_bc     = ws + OFF_MEMBC;
    float* head_w     = ws + OFF_HEADW;
    float* head_b     = ws + OFF_HEADB;

    prep_kernel<<<64, 256, 0, stream>>>(enc_bih, enc_bhh, mem_bih, mem_bhh,
                                        actor_w, actor_b, critic_w, critic_b,
                                        enc_bc, mem_bc, head_w, head_b);
    conv_frag_perm_kernel<<<20, 256, 0, stream>>>(conv2_w, cw2h, cw2l, 16, 5);
    conv_frag_perm_kernel<<<36, 256, 0, stream>>>(conv3_w, cw3h, cw3l, 32, 9);
    gemm_frag_kernel<<<1568, 256, 0, stream>>>(fc_w, fcw_h, fcw_l, 1568, 49, 16);
    conv_kernel<<<TBTOT, 256, 0, stream>>>(x_img, conv1_w, conv1_b,
                                           cw2h, cw2l, cw3h, cw3l, convAh, convAl);
    mfma_gemm<true><<<dim3(128, 4), 256, 0, stream>>>(convAh, convAl, fcw_h, fcw_l,
                                                      fc_b, img_hidden, 256, 1568, 49);
    // conv A region dead from here; LSTM fragments + state may now use it
    split_frag_kernel<<<65536, 256, 0, stream>>>(mem_Whh, mem_wf_hi, mem_wf_lo, 1024);
    split_frag_kernel<<<4096, 256, 0, stream>>>(enc_Whh, enc_wf_hi, enc_wf_lo, 256);
    gemm_frag_kernel<<<4608, 256, 0, stream>>>(mem_Wih, wihf_h, wihf_l, 288, 9, 256);
    init_state_kernel<<<128, 256, 0, stream>>>(enc_h0, enc_c0, hbe_hi, hbe_lo, cbe, BATCH * 256);
    init_state_kernel<<<512, 256, 0, stream>>>(mem_h0, mem_c0, hbm_hi, hbm_lo, cbm, BATCH * 1024);
    embed_kernel<<<1024, 256, 0, stream>>>(x_lang, emb, lang_in);
    gemm64<false><<<dim3(128, 16), 64, 0, stream>>>(lang_in, enc_Wih, enc_bc, enc_xW, TBTOT, 1024, 32);

    // ---- encoder scan (NB=32, dim3 grid) ----
    {
        int cur = 0;
        for (int st = 0; st < T_STEPS; ++st) {
            lstm_step_kernel<256, 32, false><<<dim3(16, 4), 256, 0, stream>>>(
                enc_xW + (size_t)st * BATCH * 1024, enc_wf_hi, enc_wf_lo, done + st,
                hbe_hi + (size_t)cur * (BATCH * 256), hbe_lo + (size_t)cur * (BATCH * 256),
                hbe_hi + (size_t)(cur ^ 1) * (BATCH * 256), hbe_lo + (size_t)(cur ^ 1) * (BATCH * 256),
                cbe, enc_hs + (size_t)st * BATCH * 256);
            cur ^= 1;
        }
    }
    gemm64<true><<<dim3(128, 1), 64, 0, stream>>>(enc_hs, lemb_w, lemb_b, lang_h, TBTOT, 32, 256);
    concat_kernel<<<TBTOT, 288, 0, stream>>>(img_hidden, lang_h, hid_h, hid_l);
    mfma_gemm<false><<<dim3(128, 64), 256, 0, stream>>>(hid_h, hid_l, wihf_h, wihf_l,
                                                        mem_bc, mem_xW, 4096, 288, 9);

    // ---- memory scan (NB=32, dim3 grid) ----
    {
        int cur = 0;
        for (int st = 0; st < T_STEPS; ++st) {
            lstm_step_kernel<1024, 32, true><<<dim3(64, 4), 256, 0, stream>>>(
                mem_xW + (size_t)st * BATCH * 4096, mem_wf_hi, mem_wf_lo, done + (size_t)st * BATCH,
                hbm_hi + (size_t)cur * (BATCH * 1024), hbm_lo + (size_t)cur * (BATCH * 1024),
                hbm_hi + (size_t)(cur ^ 1) * (BATCH * 1024), hbm_lo + (size_t)(cur ^ 1) * (BATCH * 1024),
                cbm, mem_hs + (size_t)st * BATCH * 1024);
            cur ^= 1;
        }
    }
    gemm64<false><<<dim3(128, 1), 64, 0, stream>>>(mem_hs, head_w, head_b, (float*)d_out, TBTOT, 16, 1024);
}

// Round 20
// 1617.353 us; speedup vs baseline: 1.0660x; 1.0305x over previous
//
#include <hip/hip_runtime.h>
#include <math.h>

#define T_STEPS 64
#define BATCH   128
#define TBTOT   8192

typedef __attribute__((ext_vector_type(8))) short bf16x8;
typedef __attribute__((ext_vector_type(4))) float f32x4;

// ---------------- workspace layout (float offsets) ----------------
// NOTE region lifetimes: [0,12845056) holds convAh/convAl during conv+fc, then is
// reused for LSTM fragments + state. State init MUST run after the fc GEMM.
static const size_t OFF_CONVH  = 0;              // [8192*1568] bf16 hi
static const size_t OFF_CONVL  = 6422528;        // [8192*1568] bf16 lo
static const size_t OFF_MWFHI  = 0;              // [4096*1024] bf16 (phase 2)
static const size_t OFF_MWFLO  = 2097152;
static const size_t OFF_EWFHI  = 4194304;        // [1024*256] bf16
static const size_t OFF_EWFLO  = 4325376;
static const size_t OFF_HBMHI  = 4456448;        // [2][128][1024] bf16
static const size_t OFF_HBMLO  = 4587520;
static const size_t OFF_HBEHI  = 4718592;        // [2][128][256] bf16
static const size_t OFF_HBELO  = 4734976;
static const size_t OFF_CBM    = 4767744;        // [128][1024] f32
static const size_t OFF_CBE    = 4898816;        // [128][256] f32
static const size_t OFF_WIHFH  = 4931584;        // [4096*288] bf16
static const size_t OFF_WIHFL  = 5521408;
static const size_t OFF_IMGH   = 12845056;       // [8192][256]
static const size_t OFF_LANGIN = 14942208;       // [8192][32]
static const size_t OFF_ENCXW  = 15204352;       // [8192][1024]
static const size_t OFF_ENCHS  = 23592960;       // [8192][256]
static const size_t OFF_LANGH  = 25690112;       // [8192][32]
static const size_t OFF_HIDH   = 25952256;       // [8192*288] bf16 hi
static const size_t OFF_HIDL   = 27131904;       // [8192*288] bf16 lo
static const size_t OFF_MEMXW  = 28311552;       // [8192][4096]
static const size_t OFF_CW2H   = 28311552;       // 5120 shorts
static const size_t OFF_CW2L   = 28314112;
static const size_t OFF_CW3H   = 28316672;       // 9216 shorts
static const size_t OFF_CW3L   = 28321280;
static const size_t OFF_FCWH   = 28325888;       // [256*1568] bf16
static const size_t OFF_FCWL   = 28526592;
static const size_t OFF_MEMHS  = 61865984;       // [8192][1024]
static const size_t OFF_ENCBC  = 70582272;       // [1024]
static const size_t OFF_MEMBC  = 70583296;       // [4096]
static const size_t OFF_HEADW  = 70587392;       // [16][1024]
static const size_t OFF_HEADB  = 70603776;       // [16]

__device__ __forceinline__ float fast_sigm(float x) { return 1.0f / (1.0f + __expf(-x)); }
__device__ __forceinline__ float fast_tanh(float x) { return 2.0f / (1.0f + __expf(-2.0f * x)) - 1.0f; }

__device__ __forceinline__ short f32_to_bf16_rne(float x) {
    unsigned u = __float_as_uint(x);
    unsigned r = (u + 0x7fffu + ((u >> 16) & 1u)) >> 16;
    return (short)r;
}
__device__ __forceinline__ float bf16s_to_f32(short s) {
    return __uint_as_float(((unsigned)(unsigned short)s) << 16);
}

// ---------------- prep ----------------
__global__ void prep_kernel(const float* __restrict__ enc_bih, const float* __restrict__ enc_bhh,
                            const float* __restrict__ mem_bih, const float* __restrict__ mem_bhh,
                            const float* __restrict__ actor_w, const float* __restrict__ actor_b,
                            const float* __restrict__ critic_w, const float* __restrict__ critic_b,
                            float* __restrict__ enc_bc, float* __restrict__ mem_bc,
                            float* __restrict__ head_w, float* __restrict__ head_b) {
    int g = blockIdx.x * 256 + threadIdx.x;
    if (g < 1024)  enc_bc[g] = enc_bih[g] + enc_bhh[g];
    if (g < 4096)  mem_bc[g] = mem_bih[g] + mem_bhh[g];
    if (g < 16384) { int j = g >> 10, k = g & 1023; head_w[g] = (j < 15) ? actor_w[j * 1024 + k] : critic_w[k]; }
    if (g < 16)    head_b[g] = (g < 15) ? actor_b[g] : critic_b[0];
}

// ---------------- init LSTM state (runs AFTER fc GEMM frees the region) ----------------
__global__ void init_state_kernel(const float* __restrict__ h0, const float* __restrict__ c0,
                                  short* __restrict__ hhi, short* __restrict__ hlo,
                                  float* __restrict__ cb, int n) {
    int g = blockIdx.x * 256 + threadIdx.x;
    if (g < n) {
        float v = h0[g];
        short a = f32_to_bf16_rne(v);
        hhi[g] = a;
        hlo[g] = f32_to_bf16_rne(v - bf16s_to_f32(a));
        cb[g] = c0[g];
    }
}

// ---------------- split Whh into MFMA-fragment-ordered bf16 hi/lo ----------------
__global__ void split_frag_kernel(const float* __restrict__ W, short* __restrict__ hi,
                                  short* __restrict__ lo, int H) {
    size_t f = (size_t)blockIdx.x * 256 + threadIdx.x;
    size_t total = (size_t)4 * H * H;
    if (f >= total) return;
    int e    = (int)(f & 7);
    int lane = (int)((f >> 3) & 63);
    size_t rest = f >> 9;
    int nks = H >> 5;
    int ks  = (int)(rest % nks);
    int qjt = (int)(rest / nks);
    int njt = H >> 4;
    int qq = qjt / njt, jt = qjt - qq * njt;
    int n = qq * H + jt * 16 + (lane & 15);
    int k = ks * 32 + (lane >> 4) * 8 + e;
    float w = W[(size_t)n * H + k];
    short a = f32_to_bf16_rne(w);
    short b = f32_to_bf16_rne(w - bf16s_to_f32(a));
    hi[f] = a; lo[f] = b;
}

// ---------------- generic GEMM weight frags (row-major K) ----------------
__global__ void gemm_frag_kernel(const float* __restrict__ W, short* __restrict__ hi,
                                 short* __restrict__ lo, int Kv, int nks, int ntot) {
    int f = blockIdx.x * 256 + threadIdx.x;
    int total = ntot * nks * 512;
    if (f >= total) return;
    int e    = f & 7;
    int lane = (f >> 3) & 63;
    int rest = f >> 9;
    int ks   = rest % nks;
    int nt   = rest / nks;
    int n = nt * 16 + (lane & 15);
    int k = ks * 32 + (lane >> 4) * 8 + e;
    float w = (k < Kv) ? W[(size_t)n * Kv + k] : 0.0f;
    short a = f32_to_bf16_rne(w);
    short b = f32_to_bf16_rne(w - bf16s_to_f32(a));
    hi[f] = a; lo[f] = b;
}

// ---------------- conv weight frags, TAP-MAJOR permuted K: k' = tap*ICN + ic ----------------
__global__ void conv_frag_perm_kernel(const float* __restrict__ W, short* __restrict__ hi,
                                      short* __restrict__ lo, int ICN, int nks) {
    int f = blockIdx.x * 256 + threadIdx.x;
    int total = 2 * nks * 512;
    if (f >= total) return;
    int e    = f & 7;
    int lane = (f >> 3) & 63;
    int rest = f >> 9;
    int ks   = rest % nks;
    int nt   = rest / nks;
    int n  = nt * 16 + (lane & 15);
    int kp = ks * 32 + (lane >> 4) * 8 + e;
    int Kv = ICN * 9;
    float w = 0.0f;
    if (kp < Kv) {
        int tap = kp / ICN, ic = kp % ICN;
        w = W[(size_t)n * Kv + ic * 9 + tap];
    }
    short a = f32_to_bf16_rne(w);
    short b = f32_to_bf16_rne(w - bf16s_to_f32(a));
    hi[f] = a; lo[f] = b;
}

// ---------------- MFMA split-bf16 GEMM, 64x64 tile ----------------
template <bool RELU>
__global__ __launch_bounds__(256) void mfma_gemm(
        const short* __restrict__ Ah, const short* __restrict__ Al,
        const short* __restrict__ Wfh, const short* __restrict__ Wfl,
        const float* __restrict__ bias, float* __restrict__ C,
        int N, int K, int KS) {
    const int t = threadIdx.x, lane = t & 63, wv = t >> 6;
    const int m0 = blockIdx.x * 64, n0 = blockIdx.y * 64;
    const int pr = m0 + wv * 16 + (lane & 15);
    const size_t abase = (size_t)pr * K + ((lane >> 4) << 3);
    const int ntg0 = n0 >> 4;
    f32x4 acc0 = {0.f,0.f,0.f,0.f}, acc1 = {0.f,0.f,0.f,0.f};
    f32x4 acc2 = {0.f,0.f,0.f,0.f}, acc3 = {0.f,0.f,0.f,0.f};
    for (int ks = 0; ks < KS; ++ks) {
        bf16x8 ah = *(const bf16x8*)&Ah[abase + (size_t)ks * 32];
        bf16x8 al = *(const bf16x8*)&Al[abase + (size_t)ks * 32];
        const bf16x8* bh0 = (const bf16x8*)Wfh + ((size_t)ntg0 * KS + ks) * 64 + lane;
        const bf16x8* bl0 = (const bf16x8*)Wfl + ((size_t)ntg0 * KS + ks) * 64 + lane;
        bf16x8 bh, bl;
        bh = bh0[0];            bl = bl0[0];
        acc0 = __builtin_amdgcn_mfma_f32_16x16x32_bf16(ah, bh, acc0, 0, 0, 0);
        acc0 = __builtin_amdgcn_mfma_f32_16x16x32_bf16(ah, bl, acc0, 0, 0, 0);
        acc0 = __builtin_amdgcn_mfma_f32_16x16x32_bf16(al, bh, acc0, 0, 0, 0);
        bh = bh0[(size_t)KS * 64]; bl = bl0[(size_t)KS * 64];
        acc1 = __builtin_amdgcn_mfma_f32_16x16x32_bf16(ah, bh, acc1, 0, 0, 0);
        acc1 = __builtin_amdgcn_mfma_f32_16x16x32_bf16(ah, bl, acc1, 0, 0, 0);
        acc1 = __builtin_amdgcn_mfma_f32_16x16x32_bf16(al, bh, acc1, 0, 0, 0);
        bh = bh0[(size_t)KS * 128]; bl = bl0[(size_t)KS * 128];
        acc2 = __builtin_amdgcn_mfma_f32_16x16x32_bf16(ah, bh, acc2, 0, 0, 0);
        acc2 = __builtin_amdgcn_mfma_f32_16x16x32_bf16(ah, bl, acc2, 0, 0, 0);
        acc2 = __builtin_amdgcn_mfma_f32_16x16x32_bf16(al, bh, acc2, 0, 0, 0);
        bh = bh0[(size_t)KS * 192]; bl = bl0[(size_t)KS * 192];
        acc3 = __builtin_amdgcn_mfma_f32_16x16x32_bf16(ah, bh, acc3, 0, 0, 0);
        acc3 = __builtin_amdgcn_mfma_f32_16x16x32_bf16(ah, bl, acc3, 0, 0, 0);
        acc3 = __builtin_amdgcn_mfma_f32_16x16x32_bf16(al, bh, acc3, 0, 0, 0);
    }
    const int rbase = m0 + wv * 16 + ((lane >> 4) << 2);
    #pragma unroll
    for (int nt = 0; nt < 4; ++nt) {
        f32x4 a = (nt == 0) ? acc0 : (nt == 1) ? acc1 : (nt == 2) ? acc2 : acc3;
        int n = n0 + nt * 16 + (lane & 15);
        float bv = bias[n];
        #pragma unroll
        for (int r = 0; r < 4; ++r) {
            float v = a[r] + bv;
            if (RELU) v = fmaxf(v, 0.0f);
            C[(size_t)(rbase + r) * N + n] = v;
        }
    }
}

// ---------------- conv stack v6: no image staging (conv1 reads global, 6 blocks/CU) ----------------
__global__ __launch_bounds__(256) void conv_kernel(const float* __restrict__ x,
        const float* __restrict__ w1, const float* __restrict__ b1,
        const short* __restrict__ w2fh, const short* __restrict__ w2fl,
        const short* __restrict__ w3fh, const short* __restrict__ w3fl,
        short* __restrict__ outh, short* __restrict__ outl) {
    __shared__ short sp[12288];                  // 24576 B total
    short* o1ch  = sp;                           // [121][24]
    short* o1cl  = sp + 2904;
    short* o2ch  = sp + 5808;                    // [81][40]
    short* o2cl  = sp + 9048;                    // ends at 12288
    const int t = threadIdx.x, lane = t & 63;
    const int wv = t >> 6;
    const int g  = lane >> 4;
    const size_t img = blockIdx.x;
    const bf16x8 zero8 = {0, 0, 0, 0, 0, 0, 0, 0};
    const float* xi = x + img * 9801;

    {   // conv1: direct global reads (waves 2-3 duplicate waves 0-1 -> L1 hits)
        const int cg2 = __builtin_amdgcn_readfirstlane(t >> 7);
        const int p = t & 127;
        if (p < 121) {
            int i = p / 11, j = p - i * 11;
            float acc[8];
            #pragma unroll
            for (int cc = 0; cc < 8; ++cc) acc[cc] = b1[cg2 * 8 + cc];
            for (int ky = 0; ky < 9; ++ky) {
                const float* irow = xi + (i * 9 + ky) * 99 + j * 9;
                float row[9];
                #pragma unroll
                for (int kx = 0; kx < 9; ++kx) row[kx] = irow[kx] * (1.0f / 255.0f);
                #pragma unroll
                for (int cc = 0; cc < 8; ++cc) {
                    const float* wr = w1 + (cg2 * 8 + cc) * 81 + ky * 9;
                    #pragma unroll
                    for (int kx = 0; kx < 9; ++kx) acc[cc] += wr[kx] * row[kx];
                }
            }
            bf16x8 vh, vl;
            #pragma unroll
            for (int cc = 0; cc < 8; ++cc) {
                float v = fmaxf(acc[cc], 0.0f);
                short h = f32_to_bf16_rne(v);
                vh[cc] = h;
                vl[cc] = f32_to_bf16_rne(v - bf16s_to_f32(h));
            }
            *(bf16x8*)&o1ch[p * 24 + cg2 * 8] = vh;
            *(bf16x8*)&o1cl[p * 24 + cg2 * 8] = vl;
        }
    }
    __syncthreads();

    {   // conv2 MFMA: k' = tap*16 + ic; fragment = ONE b128 from o1c
        const int ic0 = (g & 1) * 8;
        int toff2[5];
        #pragma unroll
        for (int ks = 0; ks < 5; ++ks) {
            int tap = 2 * ks + (g >> 1);
            if (tap > 8) tap = 8;
            toff2[ks] = (tap / 3) * 11 + (tap % 3);
        }
        #pragma unroll
        for (int i = 0; i < 3; ++i) {
            int tau = wv + 4 * i;
            int Mt = tau >> 1, Nt = tau & 1;
            int p = Mt * 16 + (lane & 15);
            int prow = (p / 9) * 11 + (p % 9);
            if (p >= 81) prow = 0;
            f32x4 acc = {0.f, 0.f, 0.f, 0.f};
            #pragma unroll
            for (int ks = 0; ks < 5; ++ks) {
                int ad = (prow + toff2[ks]) * 24 + ic0;
                bf16x8 ah = *(const bf16x8*)&o1ch[ad];
                bf16x8 al = *(const bf16x8*)&o1cl[ad];
                if (ks == 4 && g >= 2) { ah = zero8; al = zero8; }
                bf16x8 bh = ((const bf16x8*)w2fh)[(Nt * 5 + ks) * 64 + lane];
                bf16x8 bl = ((const bf16x8*)w2fl)[(Nt * 5 + ks) * 64 + lane];
                acc = __builtin_amdgcn_mfma_f32_16x16x32_bf16(ah, bh, acc, 0, 0, 0);
                acc = __builtin_amdgcn_mfma_f32_16x16x32_bf16(ah, bl, acc, 0, 0, 0);
                acc = __builtin_amdgcn_mfma_f32_16x16x32_bf16(al, bh, acc, 0, 0, 0);
            }
            int c = Nt * 16 + (lane & 15);
            #pragma unroll
            for (int r = 0; r < 4; ++r) {
                int pp = Mt * 16 + ((lane >> 4) << 2) + r;
                if (pp < 81) {
                    float v = fmaxf(acc[r], 0.0f);
                    short h = f32_to_bf16_rne(v);
                    o2ch[pp * 40 + c] = h;
                    o2cl[pp * 40 + c] = f32_to_bf16_rne(v - bf16s_to_f32(h));
                }
            }
        }
    }
    __syncthreads();

    {   // conv3 MFMA: k' = tap*32 + ic; K=288 exact
        short* ogh = outh + img * 1568;
        short* ogl = outl + img * 1568;
        #pragma unroll
        for (int i = 0; i < 2; ++i) {
            int tau = wv + 4 * i;
            int Mt = tau >> 1, Nt = tau & 1;
            int p = Mt * 16 + (lane & 15);
            int prow = (p / 7) * 9 + (p % 7);
            if (p >= 49) prow = 0;
            f32x4 acc = {0.f, 0.f, 0.f, 0.f};
            #pragma unroll
            for (int ks = 0; ks < 9; ++ks) {
                int toff = (ks / 3) * 9 + (ks % 3);
                int ad = (prow + toff) * 40 + g * 8;
                bf16x8 ah = *(const bf16x8*)&o2ch[ad];
                bf16x8 al = *(const bf16x8*)&o2cl[ad];
                bf16x8 bh = ((const bf16x8*)w3fh)[(Nt * 9 + ks) * 64 + lane];
                bf16x8 bl = ((const bf16x8*)w3fl)[(Nt * 9 + ks) * 64 + lane];
                acc = __builtin_amdgcn_mfma_f32_16x16x32_bf16(ah, bh, acc, 0, 0, 0);
                acc = __builtin_amdgcn_mfma_f32_16x16x32_bf16(ah, bl, acc, 0, 0, 0);
                acc = __builtin_amdgcn_mfma_f32_16x16x32_bf16(al, bh, acc, 0, 0, 0);
            }
            int c = Nt * 16 + (lane & 15);
            #pragma unroll
            for (int r = 0; r < 4; ++r) {
                int pp = Mt * 16 + ((lane >> 4) << 2) + r;
                if (pp < 49) {
                    float v = fmaxf(acc[r], 0.0f);
                    short h = f32_to_bf16_rne(v);
                    ogh[c * 49 + pp] = h;
                    ogl[c * 49 + pp] = f32_to_bf16_rne(v - bf16s_to_f32(h));
                }
            }
        }
    }
}

// ---------------- generic tiled fp32 GEMM (small cases) ----------------
template <bool RELU>
__global__ __launch_bounds__(64) void gemm64(const float* __restrict__ A, const float* __restrict__ W,
                                             const float* __restrict__ bias, float* __restrict__ C,
                                             int M, int N, int K) {
    __shared__ float At[32][68];
    __shared__ float Wt[32][68];
    const int m0 = blockIdx.x * 64, n0 = blockIdx.y * 64;
    const int t = threadIdx.x;
    const int tx = t & 7, ty = t >> 3;
    float acc[8][8] = {};
    for (int kc = 0; kc < K; kc += 32) {
        #pragma unroll
        for (int i = 0; i < 8; ++i) {
            int e = t + i * 64;
            int row = e >> 3, c4 = (e & 7) * 4;
            float4 v = *(const float4*)&A[(size_t)(m0 + row) * K + kc + c4];
            At[c4 + 0][row] = v.x; At[c4 + 1][row] = v.y; At[c4 + 2][row] = v.z; At[c4 + 3][row] = v.w;
            int n = n0 + row;
            float4 wv = make_float4(0.f, 0.f, 0.f, 0.f);
            if (n < N) wv = *(const float4*)&W[(size_t)n * K + kc + c4];
            Wt[c4 + 0][row] = wv.x; Wt[c4 + 1][row] = wv.y; Wt[c4 + 2][row] = wv.z; Wt[c4 + 3][row] = wv.w;
        }
        __syncthreads();
        #pragma unroll
        for (int kk = 0; kk < 32; ++kk) {
            float4 a0 = *(const float4*)&At[kk][ty * 8];
            float4 a1 = *(const float4*)&At[kk][ty * 8 + 4];
            float4 b0 = *(const float4*)&Wt[kk][tx * 8];
            float4 b1 = *(const float4*)&Wt[kk][tx * 8 + 4];
            float a[8] = {a0.x, a0.y, a0.z, a0.w, a1.x, a1.y, a1.z, a1.w};
            float b[8] = {b0.x, b0.y, b0.z, b0.w, b1.x, b1.y, b1.z, b1.w};
            #pragma unroll
            for (int i = 0; i < 8; ++i)
                #pragma unroll
                for (int j = 0; j < 8; ++j) acc[i][j] += a[i] * b[j];
        }
        __syncthreads();
    }
    #pragma unroll
    for (int i = 0; i < 8; ++i) {
        int m = m0 + ty * 8 + i;
        #pragma unroll
        for (int j = 0; j < 8; ++j) {
            int n = n0 + tx * 8 + j;
            if (n < N) {
                float v = acc[i][j] + bias[n];
                if (RELU) v = fmaxf(v, 0.0f);
                C[(size_t)m * N + n] = v;
            }
        }
    }
}

// ---------------- embedding ----------------
__global__ void embed_kernel(const int* __restrict__ lang, const float* __restrict__ emb,
                             float* __restrict__ out) {
    int g = blockIdx.x * 256 + threadIdx.x;
    if (g < TBTOT * 32) { int r = g >> 5, c = g & 31; out[g] = emb[lang[r] * 32 + c]; }
}

// ---------------- concat -> split bf16 hidden ----------------
__global__ void concat_kernel(const float* __restrict__ img_h, const float* __restrict__ lang_h,
                              short* __restrict__ outh, short* __restrict__ outl) {
    int r = blockIdx.x, c = threadIdx.x;
    float v = (c < 256) ? img_h[r * 256 + c] : lang_h[r * 32 + (c - 256)];
    short h = f32_to_bf16_rne(v);
    outh[r * 288 + c] = h;
    outl[r * 288 + c] = f32_to_bf16_rne(v - bf16s_to_f32(h));
}

// ---------------- ONE LSTM STEP, NB batch rows per block (dim3 grid) ----------------
template <int H, int NB, bool PER_ENV>
__global__ __launch_bounds__(256) void lstm_step_kernel(
        const float* __restrict__ xw_s,    // [B][4H] for this step
        const short* __restrict__ wf_hi,
        const short* __restrict__ wf_lo,
        const float* __restrict__ done_s,  // PER_ENV ? [B] : [1] scalar
        const short* __restrict__ hs_hi, const short* __restrict__ hs_lo,
        short* __restrict__ hd_hi, short* __restrict__ hd_lo,
        float* __restrict__ cbuf,
        float* __restrict__ hs_out) {
    constexpr int CK   = 8192 / NB;
    constexpr int SEGS = CK / 8;
    constexpr int NMT  = NB / 16;
    constexpr int NCH  = H / CK;
    constexpr int KSL  = CK / 32;
    __shared__ bf16x8 lsA[2][1024];
    __shared__ float  gbuf[4][NB][16];
    const int t    = threadIdx.x;
    const int lane = t & 63;
    const int q    = t >> 6;
    const int jt   = blockIdx.x;
    const int j0   = jt * 16;
    const int b0   = blockIdx.y * NB;
    const int jl   = t & 15, bl = (t >> 4) & 15;
    const int jg   = j0 + jl;
    const int njt  = H >> 4, nks = H >> 5;

    const float m_step = PER_ENV ? 0.0f : (1.0f - done_s[0]);

    float xg[NMT][4], m_e[NMT];
    #pragma unroll
    for (int e = 0; e < NMT; ++e) {
        int bgl = b0 + bl + e * 16;
        const float* xr = xw_s + (size_t)bgl * (4 * H);
        #pragma unroll
        for (int g4 = 0; g4 < 4; ++g4) xg[e][g4] = xr[g4 * H + jg];
        m_e[e] = PER_ENV ? (1.0f - done_s[bgl]) : m_step;
    }

    f32x4 acc[NMT];
    #pragma unroll
    for (int m = 0; m < NMT; ++m) acc[m] = (f32x4){0.f, 0.f, 0.f, 0.f};
    const bf16x8* bfh = (const bf16x8*)wf_hi + (size_t)(q * njt + jt) * nks * 64;
    const bf16x8* bfl = (const bf16x8*)wf_lo + (size_t)(q * njt + jt) * nks * 64;
    const bf16x8 zero8 = {0, 0, 0, 0, 0, 0, 0, 0};

    for (int cch = 0; cch < NCH; ++cch) {
        const int k0 = cch * CK;
        #pragma unroll
        for (int i = 0; i < 4; ++i) {
            int idx = i * 256 + t;
            int row = idx / SEGS, seg = idx % SEGS;
            float m = PER_ENV ? (1.0f - done_s[b0 + row]) : m_step;
            int slot = seg * NB + ((row ^ seg) & (NB - 1));
            bf16x8 vh = *(const bf16x8*)&hs_hi[(size_t)(b0 + row) * H + k0 + seg * 8];
            bf16x8 vl = *(const bf16x8*)&hs_lo[(size_t)(b0 + row) * H + k0 + seg * 8];
            if (m == 0.0f) { vh = zero8; vl = zero8; }
            lsA[0][slot] = vh;
            lsA[1][slot] = vl;
        }
        __syncthreads();
        #pragma unroll
        for (int ksl = 0; ksl < KSL; ++ksl) {
            int ks = cch * KSL + ksl;
            bf16x8 b_hi = bfh[(size_t)ks * 64 + lane];
            bf16x8 b_lo = bfl[(size_t)ks * 64 + lane];
            int kgrp = ksl * 4 + (lane >> 4);
            #pragma unroll
            for (int mt = 0; mt < NMT; ++mt) {
                int row = mt * 16 + (lane & 15);
                int slot = kgrp * NB + ((row ^ kgrp) & (NB - 1));
                bf16x8 ah = lsA[0][slot];
                bf16x8 al = lsA[1][slot];
                acc[mt] = __builtin_amdgcn_mfma_f32_16x16x32_bf16(ah, b_hi, acc[mt], 0, 0, 0);
                acc[mt] = __builtin_amdgcn_mfma_f32_16x16x32_bf16(ah, b_lo, acc[mt], 0, 0, 0);
                acc[mt] = __builtin_amdgcn_mfma_f32_16x16x32_bf16(al, b_hi, acc[mt], 0, 0, 0);
            }
        }
        __syncthreads();
    }

    // gate partial write (C/D layout: col=lane&15, row=(lane>>4)*4+r)
    #pragma unroll
    for (int mt = 0; mt < NMT; ++mt)
        #pragma unroll
        for (int r = 0; r < 4; ++r)
            gbuf[q][mt * 16 + ((lane >> 4) << 2) + r][lane & 15] = acc[mt][r];
    __syncthreads();

    #pragma unroll
    for (int e = 0; e < NMT; ++e) {
        int b_loc = bl + e * 16;
        int bgl = b0 + b_loc;
        float m = m_e[e];
        float gi = gbuf[0][b_loc][jl] + xg[e][0];
        float gf = gbuf[1][b_loc][jl] + xg[e][1];
        float gg = gbuf[2][b_loc][jl] + xg[e][2];
        float go = gbuf[3][b_loc][jl] + xg[e][3];
        size_t ci = (size_t)bgl * H + jg;
        float cc = fast_sigm(gf) * (cbuf[ci] * m) + fast_sigm(gi) * fast_tanh(gg);
        float hh = fast_sigm(go) * fast_tanh(cc);
        cbuf[ci] = cc;
        hs_out[ci] = hh;
        short hhi = f32_to_bf16_rne(hh);
        short hlo = f32_to_bf16_rne(hh - bf16s_to_f32(hhi));
        hd_hi[ci] = hhi;
        hd_lo[ci] = hlo;
    }
}

extern "C" void kernel_launch(void* const* d_in, const int* in_sizes, int n_in,
                              void* d_out, int out_size, void* d_ws, size_t ws_size,
                              hipStream_t stream) {
    const float* x_img    = (const float*)d_in[0];
    const int*   x_lang   = (const int*)d_in[1];
    const float* done     = (const float*)d_in[2];
    const float* enc_h0   = (const float*)d_in[3];
    const float* enc_c0   = (const float*)d_in[4];
    const float* mem_h0   = (const float*)d_in[5];
    const float* mem_c0   = (const float*)d_in[6];
    const float* emb      = (const float*)d_in[7];
    const float* conv1_w  = (const float*)d_in[8];
    const float* conv1_b  = (const float*)d_in[9];
    const float* conv2_w  = (const float*)d_in[10];
    const float* conv2_b  = (const float*)d_in[11];
    const float* conv3_w  = (const float*)d_in[12];
    const float* conv3_b  = (const float*)d_in[13];
    const float* fc_w     = (const float*)d_in[14];
    const float* fc_b     = (const float*)d_in[15];
    const float* enc_Wih  = (const float*)d_in[16];
    const float* enc_Whh  = (const float*)d_in[17];
    const float* enc_bih  = (const float*)d_in[18];
    const float* enc_bhh  = (const float*)d_in[19];
    const float* lemb_w   = (const float*)d_in[20];
    const float* lemb_b   = (const float*)d_in[21];
    const float* mem_Wih  = (const float*)d_in[22];
    const float* mem_Whh  = (const float*)d_in[23];
    const float* mem_bih  = (const float*)d_in[24];
    const float* mem_bhh  = (const float*)d_in[25];
    const float* actor_w  = (const float*)d_in[26];
    const float* actor_b  = (const float*)d_in[27];
    const float* critic_w = (const float*)d_in[28];
    const float* critic_b = (const float*)d_in[29];

    float* ws = (float*)d_ws;
    short* convAh     = (short*)(ws + OFF_CONVH);
    short* convAl     = (short*)(ws + OFF_CONVL);
    short* mem_wf_hi  = (short*)(ws + OFF_MWFHI);
    short* mem_wf_lo  = (short*)(ws + OFF_MWFLO);
    short* enc_wf_hi  = (short*)(ws + OFF_EWFHI);
    short* enc_wf_lo  = (short*)(ws + OFF_EWFLO);
    short* hbm_hi     = (short*)(ws + OFF_HBMHI);
    short* hbm_lo     = (short*)(ws + OFF_HBMLO);
    short* hbe_hi     = (short*)(ws + OFF_HBEHI);
    short* hbe_lo     = (short*)(ws + OFF_HBELO);
    float* cbm        = ws + OFF_CBM;
    float* cbe        = ws + OFF_CBE;
    short* wihf_h     = (short*)(ws + OFF_WIHFH);
    short* wihf_l     = (short*)(ws + OFF_WIHFL);
    short* cw2h       = (short*)(ws + OFF_CW2H);
    short* cw2l       = (short*)(ws + OFF_CW2L);
    short* cw3h       = (short*)(ws + OFF_CW3H);
    short* cw3l       = (short*)(ws + OFF_CW3L);
    short* fcw_h      = (short*)(ws + OFF_FCWH);
    short* fcw_l      = (short*)(ws + OFF_FCWL);
    float* img_hidden = ws + OFF_IMGH;
    float* lang_in    = ws + OFF_LANGIN;
    float* enc_xW     = ws + OFF_ENCXW;
    float* enc_hs     = ws + OFF_ENCHS;
    float* lang_h     = ws + OFF_LANGH;
    short* hid_h      = (short*)(ws + OFF_HIDH);
    short* hid_l      = (short*)(ws + OFF_HIDL);
    float* mem_xW     = ws + OFF_MEMXW;
    float* mem_hs     = ws + OFF_MEMHS;
    float* enc_bc     = ws + OFF_ENCBC;
    float* mem_bc     = ws + OFF_MEMBC;
    float* head_w     = ws + OFF_HEADW;
    float* head_b     = ws + OFF_HEADB;

    prep_kernel<<<64, 256, 0, stream>>>(enc_bih, enc_bhh, mem_bih, mem_bhh,
                                        actor_w, actor_b, critic_w, critic_b,
                                        enc_bc, mem_bc, head_w, head_b);
    conv_frag_perm_kernel<<<20, 256, 0, stream>>>(conv2_w, cw2h, cw2l, 16, 5);
    conv_frag_perm_kernel<<<36, 256, 0, stream>>>(conv3_w, cw3h, cw3l, 32, 9);
    gemm_frag_kernel<<<1568, 256, 0, stream>>>(fc_w, fcw_h, fcw_l, 1568, 49, 16);
    conv_kernel<<<TBTOT, 256, 0, stream>>>(x_img, conv1_w, conv1_b,
                                           cw2h, cw2l, cw3h, cw3l, convAh, convAl);
    mfma_gemm<true><<<dim3(128, 4), 256, 0, stream>>>(convAh, convAl, fcw_h, fcw_l,
                                                      fc_b, img_hidden, 256, 1568, 49);
    // conv A region dead from here; LSTM fragments + state may now use it
    split_frag_kernel<<<65536, 256, 0, stream>>>(mem_Whh, mem_wf_hi, mem_wf_lo, 1024);
    split_frag_kernel<<<4096, 256, 0, stream>>>(enc_Whh, enc_wf_hi, enc_wf_lo, 256);
    gemm_frag_kernel<<<4608, 256, 0, stream>>>(mem_Wih, wihf_h, wihf_l, 288, 9, 256);
    init_state_kernel<<<128, 256, 0, stream>>>(enc_h0, enc_c0, hbe_hi, hbe_lo, cbe, BATCH * 256);
    init_state_kernel<<<512, 256, 0, stream>>>(mem_h0, mem_c0, hbm_hi, hbm_lo, cbm, BATCH * 1024);
    embed_kernel<<<1024, 256, 0, stream>>>(x_lang, emb, lang_in);
    gemm64<false><<<dim3(128, 16), 64, 0, stream>>>(lang_in, enc_Wih, enc_bc, enc_xW, TBTOT, 1024, 32);

    // ---- encoder scan (NB=32, dim3 grid) ----
    {
        int cur = 0;
        for (int st = 0; st < T_STEPS; ++st) {
            lstm_step_kernel<256, 32, false><<<dim3(16, 4), 256, 0, stream>>>(
                enc_xW + (size_t)st * BATCH * 1024, enc_wf_hi, enc_wf_lo, done + st,
                hbe_hi + (size_t)cur * (BATCH * 256), hbe_lo + (size_t)cur * (BATCH * 256),
                hbe_hi + (size_t)(cur ^ 1) * (BATCH * 256), hbe_lo + (size_t)(cur ^ 1) * (BATCH * 256),
                cbe, enc_hs + (size_t)st * BATCH * 256);
            cur ^= 1;
        }
    }
    gemm64<true><<<dim3(128, 1), 64, 0, stream>>>(enc_hs, lemb_w, lemb_b, lang_h, TBTOT, 32, 256);
    concat_kernel<<<TBTOT, 288, 0, stream>>>(img_hidden, lang_h, hid_h, hid_l);
    mfma_gemm<false><<<dim3(128, 64), 256, 0, stream>>>(hid_h, hid_l, wihf_h, wihf_l,
                                                        mem_bc, mem_xW, 4096, 288, 9);

    // ---- memory scan (NB=32, dim3 grid) ----
    {
        int cur = 0;
        for (int st = 0; st < T_STEPS; ++st) {
            lstm_step_kernel<1024, 32, true><<<dim3(64, 4), 256, 0, stream>>>(
                mem_xW + (size_t)st * BATCH * 4096, mem_wf_hi, mem_wf_lo, done + (size_t)st * BATCH,
                hbm_hi + (size_t)cur * (BATCH * 1024), hbm_lo + (size_t)cur * (BATCH * 1024),
                hbm_hi + (size_t)(cur ^ 1) * (BATCH * 1024), hbm_lo + (size_t)(cur ^ 1) * (BATCH * 1024),
                cbm, mem_hs + (size_t)st * BATCH * 1024);
            cur ^= 1;
        }
    }
    gemm64<false><<<dim3(128, 1), 64, 0, stream>>>(mem_hs, head_w, head_b, (float*)d_out, TBTOT, 16, 1024);
}

// Round 21
// 1470.111 us; speedup vs baseline: 1.1728x; 1.1002x over previous
//
#include <hip/hip_runtime.h>
#include <math.h>

#define T_STEPS 64
#define BATCH   128
#define TBTOT   8192

typedef __attribute__((ext_vector_type(8))) short bf16x8;
typedef __attribute__((ext_vector_type(4))) float f32x4;

// ---------------- workspace layout (float offsets) ----------------
// NOTE region lifetimes: [0,12845056) holds convAh/convAl during conv+fc, then is
// reused for LSTM fragments + state. State init MUST run after the fc GEMM.
static const size_t OFF_CONVH  = 0;              // [8192*1568] bf16 hi
static const size_t OFF_CONVL  = 6422528;        // [8192*1568] bf16 lo
static const size_t OFF_MWFHI  = 0;              // [4096*1024] bf16 (phase 2)
static const size_t OFF_MWFLO  = 2097152;
static const size_t OFF_EWFHI  = 4194304;        // [1024*256] bf16
static const size_t OFF_EWFLO  = 4325376;
static const size_t OFF_HBMHI  = 4456448;        // [2][128][1024] bf16
static const size_t OFF_HBMLO  = 4587520;
static const size_t OFF_HBEHI  = 4718592;        // [2][128][256] bf16
static const size_t OFF_HBELO  = 4734976;
static const size_t OFF_CBM    = 4767744;        // [128][1024] f32
static const size_t OFF_CBE    = 4898816;        // [128][256] f32
static const size_t OFF_WIHFH  = 4931584;        // [4096*288] bf16
static const size_t OFF_WIHFL  = 5521408;
static const size_t OFF_IMGH   = 12845056;       // [8192][256]
static const size_t OFF_LANGIN = 14942208;       // [8192][32]
static const size_t OFF_ENCXW  = 15204352;       // [8192][1024]
static const size_t OFF_ENCHS  = 23592960;       // [8192][256]
static const size_t OFF_LANGH  = 25690112;       // [8192][32]
static const size_t OFF_HIDH   = 25952256;       // [8192*288] bf16 hi
static const size_t OFF_HIDL   = 27131904;       // [8192*288] bf16 lo
static const size_t OFF_MEMXW  = 28311552;       // [8192][4096]
static const size_t OFF_CW2H   = 28311552;       // 5120 shorts
static const size_t OFF_CW2L   = 28314112;
static const size_t OFF_CW3H   = 28316672;       // 9216 shorts
static const size_t OFF_CW3L   = 28321280;
static const size_t OFF_FCWH   = 28325888;       // [256*1568] bf16
static const size_t OFF_FCWL   = 28526592;
static const size_t OFF_MEMHS  = 61865984;       // [8192][1024]
static const size_t OFF_ENCBC  = 70582272;       // [1024]
static const size_t OFF_MEMBC  = 70583296;       // [4096]
static const size_t OFF_HEADW  = 70587392;       // [16][1024]
static const size_t OFF_HEADB  = 70603776;       // [16]

__device__ __forceinline__ float fast_sigm(float x) { return 1.0f / (1.0f + __expf(-x)); }
__device__ __forceinline__ float fast_tanh(float x) { return 2.0f / (1.0f + __expf(-2.0f * x)) - 1.0f; }

__device__ __forceinline__ short f32_to_bf16_rne(float x) {
    unsigned u = __float_as_uint(x);
    unsigned r = (u + 0x7fffu + ((u >> 16) & 1u)) >> 16;
    return (short)r;
}
__device__ __forceinline__ float bf16s_to_f32(short s) {
    return __uint_as_float(((unsigned)(unsigned short)s) << 16);
}

// ---------------- prep ----------------
__global__ void prep_kernel(const float* __restrict__ enc_bih, const float* __restrict__ enc_bhh,
                            const float* __restrict__ mem_bih, const float* __restrict__ mem_bhh,
                            const float* __restrict__ actor_w, const float* __restrict__ actor_b,
                            const float* __restrict__ critic_w, const float* __restrict__ critic_b,
                            float* __restrict__ enc_bc, float* __restrict__ mem_bc,
                            float* __restrict__ head_w, float* __restrict__ head_b) {
    int g = blockIdx.x * 256 + threadIdx.x;
    if (g < 1024)  enc_bc[g] = enc_bih[g] + enc_bhh[g];
    if (g < 4096)  mem_bc[g] = mem_bih[g] + mem_bhh[g];
    if (g < 16384) { int j = g >> 10, k = g & 1023; head_w[g] = (j < 15) ? actor_w[j * 1024 + k] : critic_w[k]; }
    if (g < 16)    head_b[g] = (g < 15) ? actor_b[g] : critic_b[0];
}

// ---------------- init LSTM state (runs AFTER fc GEMM frees the region) ----------------
__global__ void init_state_kernel(const float* __restrict__ h0, const float* __restrict__ c0,
                                  short* __restrict__ hhi, short* __restrict__ hlo,
                                  float* __restrict__ cb, int n) {
    int g = blockIdx.x * 256 + threadIdx.x;
    if (g < n) {
        float v = h0[g];
        short a = f32_to_bf16_rne(v);
        hhi[g] = a;
        hlo[g] = f32_to_bf16_rne(v - bf16s_to_f32(a));
        cb[g] = c0[g];
    }
}

// ---------------- split Whh into MFMA-fragment-ordered bf16 hi/lo ----------------
__global__ void split_frag_kernel(const float* __restrict__ W, short* __restrict__ hi,
                                  short* __restrict__ lo, int H) {
    size_t f = (size_t)blockIdx.x * 256 + threadIdx.x;
    size_t total = (size_t)4 * H * H;
    if (f >= total) return;
    int e    = (int)(f & 7);
    int lane = (int)((f >> 3) & 63);
    size_t rest = f >> 9;
    int nks = H >> 5;
    int ks  = (int)(rest % nks);
    int qjt = (int)(rest / nks);
    int njt = H >> 4;
    int qq = qjt / njt, jt = qjt - qq * njt;
    int n = qq * H + jt * 16 + (lane & 15);
    int k = ks * 32 + (lane >> 4) * 8 + e;
    float w = W[(size_t)n * H + k];
    short a = f32_to_bf16_rne(w);
    short b = f32_to_bf16_rne(w - bf16s_to_f32(a));
    hi[f] = a; lo[f] = b;
}

// ---------------- generic GEMM weight frags (row-major K) ----------------
__global__ void gemm_frag_kernel(const float* __restrict__ W, short* __restrict__ hi,
                                 short* __restrict__ lo, int Kv, int nks, int ntot) {
    int f = blockIdx.x * 256 + threadIdx.x;
    int total = ntot * nks * 512;
    if (f >= total) return;
    int e    = f & 7;
    int lane = (f >> 3) & 63;
    int rest = f >> 9;
    int ks   = rest % nks;
    int nt   = rest / nks;
    int n = nt * 16 + (lane & 15);
    int k = ks * 32 + (lane >> 4) * 8 + e;
    float w = (k < Kv) ? W[(size_t)n * Kv + k] : 0.0f;
    short a = f32_to_bf16_rne(w);
    short b = f32_to_bf16_rne(w - bf16s_to_f32(a));
    hi[f] = a; lo[f] = b;
}

// ---------------- conv weight frags, TAP-MAJOR permuted K: k' = tap*ICN + ic ----------------
__global__ void conv_frag_perm_kernel(const float* __restrict__ W, short* __restrict__ hi,
                                      short* __restrict__ lo, int ICN, int nks) {
    int f = blockIdx.x * 256 + threadIdx.x;
    int total = 2 * nks * 512;
    if (f >= total) return;
    int e    = f & 7;
    int lane = (f >> 3) & 63;
    int rest = f >> 9;
    int ks   = rest % nks;
    int nt   = rest / nks;
    int n  = nt * 16 + (lane & 15);
    int kp = ks * 32 + (lane >> 4) * 8 + e;
    int Kv = ICN * 9;
    float w = 0.0f;
    if (kp < Kv) {
        int tap = kp / ICN, ic = kp % ICN;
        w = W[(size_t)n * Kv + ic * 9 + tap];
    }
    short a = f32_to_bf16_rne(w);
    short b = f32_to_bf16_rne(w - bf16s_to_f32(a));
    hi[f] = a; lo[f] = b;
}

// ---------------- MFMA split-bf16 GEMM, 64x64 tile ----------------
template <bool RELU>
__global__ __launch_bounds__(256) void mfma_gemm(
        const short* __restrict__ Ah, const short* __restrict__ Al,
        const short* __restrict__ Wfh, const short* __restrict__ Wfl,
        const float* __restrict__ bias, float* __restrict__ C,
        int N, int K, int KS) {
    const int t = threadIdx.x, lane = t & 63, wv = t >> 6;
    const int m0 = blockIdx.x * 64, n0 = blockIdx.y * 64;
    const int pr = m0 + wv * 16 + (lane & 15);
    const size_t abase = (size_t)pr * K + ((lane >> 4) << 3);
    const int ntg0 = n0 >> 4;
    f32x4 acc0 = {0.f,0.f,0.f,0.f}, acc1 = {0.f,0.f,0.f,0.f};
    f32x4 acc2 = {0.f,0.f,0.f,0.f}, acc3 = {0.f,0.f,0.f,0.f};
    for (int ks = 0; ks < KS; ++ks) {
        bf16x8 ah = *(const bf16x8*)&Ah[abase + (size_t)ks * 32];
        bf16x8 al = *(const bf16x8*)&Al[abase + (size_t)ks * 32];
        const bf16x8* bh0 = (const bf16x8*)Wfh + ((size_t)ntg0 * KS + ks) * 64 + lane;
        const bf16x8* bl0 = (const bf16x8*)Wfl + ((size_t)ntg0 * KS + ks) * 64 + lane;
        bf16x8 bh, bl;
        bh = bh0[0];            bl = bl0[0];
        acc0 = __builtin_amdgcn_mfma_f32_16x16x32_bf16(ah, bh, acc0, 0, 0, 0);
        acc0 = __builtin_amdgcn_mfma_f32_16x16x32_bf16(ah, bl, acc0, 0, 0, 0);
        acc0 = __builtin_amdgcn_mfma_f32_16x16x32_bf16(al, bh, acc0, 0, 0, 0);
        bh = bh0[(size_t)KS * 64]; bl = bl0[(size_t)KS * 64];
        acc1 = __builtin_amdgcn_mfma_f32_16x16x32_bf16(ah, bh, acc1, 0, 0, 0);
        acc1 = __builtin_amdgcn_mfma_f32_16x16x32_bf16(ah, bl, acc1, 0, 0, 0);
        acc1 = __builtin_amdgcn_mfma_f32_16x16x32_bf16(al, bh, acc1, 0, 0, 0);
        bh = bh0[(size_t)KS * 128]; bl = bl0[(size_t)KS * 128];
        acc2 = __builtin_amdgcn_mfma_f32_16x16x32_bf16(ah, bh, acc2, 0, 0, 0);
        acc2 = __builtin_amdgcn_mfma_f32_16x16x32_bf16(ah, bl, acc2, 0, 0, 0);
        acc2 = __builtin_amdgcn_mfma_f32_16x16x32_bf16(al, bh, acc2, 0, 0, 0);
        bh = bh0[(size_t)KS * 192]; bl = bl0[(size_t)KS * 192];
        acc3 = __builtin_amdgcn_mfma_f32_16x16x32_bf16(ah, bh, acc3, 0, 0, 0);
        acc3 = __builtin_amdgcn_mfma_f32_16x16x32_bf16(ah, bl, acc3, 0, 0, 0);
        acc3 = __builtin_amdgcn_mfma_f32_16x16x32_bf16(al, bh, acc3, 0, 0, 0);
    }
    const int rbase = m0 + wv * 16 + ((lane >> 4) << 2);
    #pragma unroll
    for (int nt = 0; nt < 4; ++nt) {
        f32x4 a = (nt == 0) ? acc0 : (nt == 1) ? acc1 : (nt == 2) ? acc2 : acc3;
        int n = n0 + nt * 16 + (lane & 15);
        float bv = bias[n];
        #pragma unroll
        for (int r = 0; r < 4; ++r) {
            float v = a[r] + bv;
            if (RELU) v = fmaxf(v, 0.0f);
            C[(size_t)(rbase + r) * N + n] = v;
        }
    }
}

// ---------------- thin-N fp32 GEMM: thread per output, full-machine grid ----------------
// C[m][n] = act(dot(A[m],W[n]) + bias[n]); grid = M*N_/256. Lanes sharing a row
// broadcast A loads from L1; W (<=64KB) stays L1-resident.
template <bool RELU, int N_>
__global__ __launch_bounds__(256) void gemm_thin(const float* __restrict__ A,
                                                 const float* __restrict__ W,
                                                 const float* __restrict__ bias,
                                                 float* __restrict__ C, int K) {
    int gid = blockIdx.x * 256 + threadIdx.x;
    int m = gid / N_, n = gid - m * N_;
    const float4* a = (const float4*)(A + (size_t)m * K);
    const float4* w = (const float4*)(W + (size_t)n * K);
    float acc = 0.0f;
    for (int k = 0; k < (K >> 2); ++k) {
        float4 av = a[k], wv = w[k];
        acc += av.x * wv.x + av.y * wv.y + av.z * wv.z + av.w * wv.w;
    }
    float v = acc + bias[n];
    if (RELU) v = fmaxf(v, 0.0f);
    C[(size_t)m * N_ + n] = v;
}

// ---------------- conv stack v6: no image staging (conv1 reads global, 6 blocks/CU) ----------------
__global__ __launch_bounds__(256) void conv_kernel(const float* __restrict__ x,
        const float* __restrict__ w1, const float* __restrict__ b1,
        const short* __restrict__ w2fh, const short* __restrict__ w2fl,
        const short* __restrict__ w3fh, const short* __restrict__ w3fl,
        short* __restrict__ outh, short* __restrict__ outl) {
    __shared__ short sp[12288];                  // 24576 B total
    short* o1ch  = sp;                           // [121][24]
    short* o1cl  = sp + 2904;
    short* o2ch  = sp + 5808;                    // [81][40]
    short* o2cl  = sp + 9048;                    // ends at 12288
    const int t = threadIdx.x, lane = t & 63;
    const int wv = t >> 6;
    const int g  = lane >> 4;
    const size_t img = blockIdx.x;
    const bf16x8 zero8 = {0, 0, 0, 0, 0, 0, 0, 0};
    const float* xi = x + img * 9801;

    {   // conv1: direct global reads (waves 2-3 duplicate waves 0-1 -> L1 hits)
        const int cg2 = __builtin_amdgcn_readfirstlane(t >> 7);
        const int p = t & 127;
        if (p < 121) {
            int i = p / 11, j = p - i * 11;
            float acc[8];
            #pragma unroll
            for (int cc = 0; cc < 8; ++cc) acc[cc] = b1[cg2 * 8 + cc];
            for (int ky = 0; ky < 9; ++ky) {
                const float* irow = xi + (i * 9 + ky) * 99 + j * 9;
                float row[9];
                #pragma unroll
                for (int kx = 0; kx < 9; ++kx) row[kx] = irow[kx] * (1.0f / 255.0f);
                #pragma unroll
                for (int cc = 0; cc < 8; ++cc) {
                    const float* wr = w1 + (cg2 * 8 + cc) * 81 + ky * 9;
                    #pragma unroll
                    for (int kx = 0; kx < 9; ++kx) acc[cc] += wr[kx] * row[kx];
                }
            }
            bf16x8 vh, vl;
            #pragma unroll
            for (int cc = 0; cc < 8; ++cc) {
                float v = fmaxf(acc[cc], 0.0f);
                short h = f32_to_bf16_rne(v);
                vh[cc] = h;
                vl[cc] = f32_to_bf16_rne(v - bf16s_to_f32(h));
            }
            *(bf16x8*)&o1ch[p * 24 + cg2 * 8] = vh;
            *(bf16x8*)&o1cl[p * 24 + cg2 * 8] = vl;
        }
    }
    __syncthreads();

    {   // conv2 MFMA: k' = tap*16 + ic; fragment = ONE b128 from o1c
        const int ic0 = (g & 1) * 8;
        int toff2[5];
        #pragma unroll
        for (int ks = 0; ks < 5; ++ks) {
            int tap = 2 * ks + (g >> 1);
            if (tap > 8) tap = 8;
            toff2[ks] = (tap / 3) * 11 + (tap % 3);
        }
        #pragma unroll
        for (int i = 0; i < 3; ++i) {
            int tau = wv + 4 * i;
            int Mt = tau >> 1, Nt = tau & 1;
            int p = Mt * 16 + (lane & 15);
            int prow = (p / 9) * 11 + (p % 9);
            if (p >= 81) prow = 0;
            f32x4 acc = {0.f, 0.f, 0.f, 0.f};
            #pragma unroll
            for (int ks = 0; ks < 5; ++ks) {
                int ad = (prow + toff2[ks]) * 24 + ic0;
                bf16x8 ah = *(const bf16x8*)&o1ch[ad];
                bf16x8 al = *(const bf16x8*)&o1cl[ad];
                if (ks == 4 && g >= 2) { ah = zero8; al = zero8; }
                bf16x8 bh = ((const bf16x8*)w2fh)[(Nt * 5 + ks) * 64 + lane];
                bf16x8 bl = ((const bf16x8*)w2fl)[(Nt * 5 + ks) * 64 + lane];
                acc = __builtin_amdgcn_mfma_f32_16x16x32_bf16(ah, bh, acc, 0, 0, 0);
                acc = __builtin_amdgcn_mfma_f32_16x16x32_bf16(ah, bl, acc, 0, 0, 0);
                acc = __builtin_amdgcn_mfma_f32_16x16x32_bf16(al, bh, acc, 0, 0, 0);
            }
            int c = Nt * 16 + (lane & 15);
            #pragma unroll
            for (int r = 0; r < 4; ++r) {
                int pp = Mt * 16 + ((lane >> 4) << 2) + r;
                if (pp < 81) {
                    float v = fmaxf(acc[r], 0.0f);
                    short h = f32_to_bf16_rne(v);
                    o2ch[pp * 40 + c] = h;
                    o2cl[pp * 40 + c] = f32_to_bf16_rne(v - bf16s_to_f32(h));
                }
            }
        }
    }
    __syncthreads();

    {   // conv3 MFMA: k' = tap*32 + ic; K=288 exact
        short* ogh = outh + img * 1568;
        short* ogl = outl + img * 1568;
        #pragma unroll
        for (int i = 0; i < 2; ++i) {
            int tau = wv + 4 * i;
            int Mt = tau >> 1, Nt = tau & 1;
            int p = Mt * 16 + (lane & 15);
            int prow = (p / 7) * 9 + (p % 7);
            if (p >= 49) prow = 0;
            f32x4 acc = {0.f, 0.f, 0.f, 0.f};
            #pragma unroll
            for (int ks = 0; ks < 9; ++ks) {
                int toff = (ks / 3) * 9 + (ks % 3);
                int ad = (prow + toff) * 40 + g * 8;
                bf16x8 ah = *(const bf16x8*)&o2ch[ad];
                bf16x8 al = *(const bf16x8*)&o2cl[ad];
                bf16x8 bh = ((const bf16x8*)w3fh)[(Nt * 9 + ks) * 64 + lane];
                bf16x8 bl = ((const bf16x8*)w3fl)[(Nt * 9 + ks) * 64 + lane];
                acc = __builtin_amdgcn_mfma_f32_16x16x32_bf16(ah, bh, acc, 0, 0, 0);
                acc = __builtin_amdgcn_mfma_f32_16x16x32_bf16(ah, bl, acc, 0, 0, 0);
                acc = __builtin_amdgcn_mfma_f32_16x16x32_bf16(al, bh, acc, 0, 0, 0);
            }
            int c = Nt * 16 + (lane & 15);
            #pragma unroll
            for (int r = 0; r < 4; ++r) {
                int pp = Mt * 16 + ((lane >> 4) << 2) + r;
                if (pp < 49) {
                    float v = fmaxf(acc[r], 0.0f);
                    short h = f32_to_bf16_rne(v);
                    ogh[c * 49 + pp] = h;
                    ogl[c * 49 + pp] = f32_to_bf16_rne(v - bf16s_to_f32(h));
                }
            }
        }
    }
}

// ---------------- generic tiled fp32 GEMM (enc_xW case) ----------------
template <bool RELU>
__global__ __launch_bounds__(64) void gemm64(const float* __restrict__ A, const float* __restrict__ W,
                                             const float* __restrict__ bias, float* __restrict__ C,
                                             int M, int N, int K) {
    __shared__ float At[32][68];
    __shared__ float Wt[32][68];
    const int m0 = blockIdx.x * 64, n0 = blockIdx.y * 64;
    const int t = threadIdx.x;
    const int tx = t & 7, ty = t >> 3;
    float acc[8][8] = {};
    for (int kc = 0; kc < K; kc += 32) {
        #pragma unroll
        for (int i = 0; i < 8; ++i) {
            int e = t + i * 64;
            int row = e >> 3, c4 = (e & 7) * 4;
            float4 v = *(const float4*)&A[(size_t)(m0 + row) * K + kc + c4];
            At[c4 + 0][row] = v.x; At[c4 + 1][row] = v.y; At[c4 + 2][row] = v.z; At[c4 + 3][row] = v.w;
            int n = n0 + row;
            float4 wv = make_float4(0.f, 0.f, 0.f, 0.f);
            if (n < N) wv = *(const float4*)&W[(size_t)n * K + kc + c4];
            Wt[c4 + 0][row] = wv.x; Wt[c4 + 1][row] = wv.y; Wt[c4 + 2][row] = wv.z; Wt[c4 + 3][row] = wv.w;
        }
        __syncthreads();
        #pragma unroll
        for (int kk = 0; kk < 32; ++kk) {
            float4 a0 = *(const float4*)&At[kk][ty * 8];
            float4 a1 = *(const float4*)&At[kk][ty * 8 + 4];
            float4 b0 = *(const float4*)&Wt[kk][tx * 8];
            float4 b1 = *(const float4*)&Wt[kk][tx * 8 + 4];
            float a[8] = {a0.x, a0.y, a0.z, a0.w, a1.x, a1.y, a1.z, a1.w};
            float b[8] = {b0.x, b0.y, b0.z, b0.w, b1.x, b1.y, b1.z, b1.w};
            #pragma unroll
            for (int i = 0; i < 8; ++i)
                #pragma unroll
                for (int j = 0; j < 8; ++j) acc[i][j] += a[i] * b[j];
        }
        __syncthreads();
    }
    #pragma unroll
    for (int i = 0; i < 8; ++i) {
        int m = m0 + ty * 8 + i;
        #pragma unroll
        for (int j = 0; j < 8; ++j) {
            int n = n0 + tx * 8 + j;
            if (n < N) {
                float v = acc[i][j] + bias[n];
                if (RELU) v = fmaxf(v, 0.0f);
                C[(size_t)m * N + n] = v;
            }
        }
    }
}

// ---------------- embedding ----------------
__global__ void embed_kernel(const int* __restrict__ lang, const float* __restrict__ emb,
                             float* __restrict__ out) {
    int g = blockIdx.x * 256 + threadIdx.x;
    if (g < TBTOT * 32) { int r = g >> 5, c = g & 31; out[g] = emb[lang[r] * 32 + c]; }
}

// ---------------- concat -> split bf16 hidden ----------------
__global__ void concat_kernel(const float* __restrict__ img_h, const float* __restrict__ lang_h,
                              short* __restrict__ outh, short* __restrict__ outl) {
    int r = blockIdx.x, c = threadIdx.x;
    float v = (c < 256) ? img_h[r * 256 + c] : lang_h[r * 32 + (c - 256)];
    short h = f32_to_bf16_rne(v);
    outh[r * 288 + c] = h;
    outl[r * 288 + c] = f32_to_bf16_rne(v - bf16s_to_f32(h));
}

// ---------------- ONE LSTM STEP, NB batch rows per block (dim3 grid) ----------------
template <int H, int NB, bool PER_ENV>
__global__ __launch_bounds__(256) void lstm_step_kernel(
        const float* __restrict__ xw_s,    // [B][4H] for this step
        const short* __restrict__ wf_hi,
        const short* __restrict__ wf_lo,
        const float* __restrict__ done_s,  // PER_ENV ? [B] : [1] scalar
        const short* __restrict__ hs_hi, const short* __restrict__ hs_lo,
        short* __restrict__ hd_hi, short* __restrict__ hd_lo,
        float* __restrict__ cbuf,
        float* __restrict__ hs_out) {
    constexpr int CK   = 8192 / NB;
    constexpr int SEGS = CK / 8;
    constexpr int NMT  = NB / 16;
    constexpr int NCH  = H / CK;
    constexpr int KSL  = CK / 32;
    __shared__ bf16x8 lsA[2][1024];
    __shared__ float  gbuf[4][NB][16];
    const int t    = threadIdx.x;
    const int lane = t & 63;
    const int q    = t >> 6;
    const int jt   = blockIdx.x;
    const int j0   = jt * 16;
    const int b0   = blockIdx.y * NB;
    const int jl   = t & 15, bl = (t >> 4) & 15;
    const int jg   = j0 + jl;
    const int njt  = H >> 4, nks = H >> 5;

    const float m_step = PER_ENV ? 0.0f : (1.0f - done_s[0]);

    float xg[NMT][4], m_e[NMT];
    #pragma unroll
    for (int e = 0; e < NMT; ++e) {
        int bgl = b0 + bl + e * 16;
        const float* xr = xw_s + (size_t)bgl * (4 * H);
        #pragma unroll
        for (int g4 = 0; g4 < 4; ++g4) xg[e][g4] = xr[g4 * H + jg];
        m_e[e] = PER_ENV ? (1.0f - done_s[bgl]) : m_step;
    }

    f32x4 acc[NMT];
    #pragma unroll
    for (int m = 0; m < NMT; ++m) acc[m] = (f32x4){0.f, 0.f, 0.f, 0.f};
    const bf16x8* bfh = (const bf16x8*)wf_hi + (size_t)(q * njt + jt) * nks * 64;
    const bf16x8* bfl = (const bf16x8*)wf_lo + (size_t)(q * njt + jt) * nks * 64;
    const bf16x8 zero8 = {0, 0, 0, 0, 0, 0, 0, 0};

    for (int cch = 0; cch < NCH; ++cch) {
        const int k0 = cch * CK;
        #pragma unroll
        for (int i = 0; i < 4; ++i) {
            int idx = i * 256 + t;
            int row = idx / SEGS, seg = idx % SEGS;
            float m = PER_ENV ? (1.0f - done_s[b0 + row]) : m_step;
            int slot = seg * NB + ((row ^ seg) & (NB - 1));
            bf16x8 vh = *(const bf16x8*)&hs_hi[(size_t)(b0 + row) * H + k0 + seg * 8];
            bf16x8 vl = *(const bf16x8*)&hs_lo[(size_t)(b0 + row) * H + k0 + seg * 8];
            if (m == 0.0f) { vh = zero8; vl = zero8; }
            lsA[0][slot] = vh;
            lsA[1][slot] = vl;
        }
        __syncthreads();
        #pragma unroll
        for (int ksl = 0; ksl < KSL; ++ksl) {
            int ks = cch * KSL + ksl;
            bf16x8 b_hi = bfh[(size_t)ks * 64 + lane];
            bf16x8 b_lo = bfl[(size_t)ks * 64 + lane];
            int kgrp = ksl * 4 + (lane >> 4);
            #pragma unroll
            for (int mt = 0; mt < NMT; ++mt) {
                int row = mt * 16 + (lane & 15);
                int slot = kgrp * NB + ((row ^ kgrp) & (NB - 1));
                bf16x8 ah = lsA[0][slot];
                bf16x8 al = lsA[1][slot];
                acc[mt] = __builtin_amdgcn_mfma_f32_16x16x32_bf16(ah, b_hi, acc[mt], 0, 0, 0);
                acc[mt] = __builtin_amdgcn_mfma_f32_16x16x32_bf16(ah, b_lo, acc[mt], 0, 0, 0);
                acc[mt] = __builtin_amdgcn_mfma_f32_16x16x32_bf16(al, b_hi, acc[mt], 0, 0, 0);
            }
        }
        __syncthreads();
    }

    // gate partial write (C/D layout: col=lane&15, row=(lane>>4)*4+r)
    #pragma unroll
    for (int mt = 0; mt < NMT; ++mt)
        #pragma unroll
        for (int r = 0; r < 4; ++r)
            gbuf[q][mt * 16 + ((lane >> 4) << 2) + r][lane & 15] = acc[mt][r];
    __syncthreads();

    #pragma unroll
    for (int e = 0; e < NMT; ++e) {
        int b_loc = bl + e * 16;
        int bgl = b0 + b_loc;
        float m = m_e[e];
        float gi = gbuf[0][b_loc][jl] + xg[e][0];
        float gf = gbuf[1][b_loc][jl] + xg[e][1];
        float gg = gbuf[2][b_loc][jl] + xg[e][2];
        float go = gbuf[3][b_loc][jl] + xg[e][3];
        size_t ci = (size_t)bgl * H + jg;
        float cc = fast_sigm(gf) * (cbuf[ci] * m) + fast_sigm(gi) * fast_tanh(gg);
        float hh = fast_sigm(go) * fast_tanh(cc);
        cbuf[ci] = cc;
        hs_out[ci] = hh;
        short hhi = f32_to_bf16_rne(hh);
        short hlo = f32_to_bf16_rne(hh - bf16s_to_f32(hhi));
        hd_hi[ci] = hhi;
        hd_lo[ci] = hlo;
    }
}

extern "C" void kernel_launch(void* const* d_in, const int* in_sizes, int n_in,
                              void* d_out, int out_size, void* d_ws, size_t ws_size,
                              hipStream_t stream) {
    const float* x_img    = (const float*)d_in[0];
    const int*   x_lang   = (const int*)d_in[1];
    const float* done     = (const float*)d_in[2];
    const float* enc_h0   = (const float*)d_in[3];
    const float* enc_c0   = (const float*)d_in[4];
    const float* mem_h0   = (const float*)d_in[5];
    const float* mem_c0   = (const float*)d_in[6];
    const float* emb      = (const float*)d_in[7];
    const float* conv1_w  = (const float*)d_in[8];
    const float* conv1_b  = (const float*)d_in[9];
    const float* conv2_w  = (const float*)d_in[10];
    const float* conv2_b  = (const float*)d_in[11];
    const float* conv3_w  = (const float*)d_in[12];
    const float* conv3_b  = (const float*)d_in[13];
    const float* fc_w     = (const float*)d_in[14];
    const float* fc_b     = (const float*)d_in[15];
    const float* enc_Wih  = (const float*)d_in[16];
    const float* enc_Whh  = (const float*)d_in[17];
    const float* enc_bih  = (const float*)d_in[18];
    const float* enc_bhh  = (const float*)d_in[19];
    const float* lemb_w   = (const float*)d_in[20];
    const float* lemb_b   = (const float*)d_in[21];
    const float* mem_Wih  = (const float*)d_in[22];
    const float* mem_Whh  = (const float*)d_in[23];
    const float* mem_bih  = (const float*)d_in[24];
    const float* mem_bhh  = (const float*)d_in[25];
    const float* actor_w  = (const float*)d_in[26];
    const float* actor_b  = (const float*)d_in[27];
    const float* critic_w = (const float*)d_in[28];
    const float* critic_b = (const float*)d_in[29];

    float* ws = (float*)d_ws;
    short* convAh     = (short*)(ws + OFF_CONVH);
    short* convAl     = (short*)(ws + OFF_CONVL);
    short* mem_wf_hi  = (short*)(ws + OFF_MWFHI);
    short* mem_wf_lo  = (short*)(ws + OFF_MWFLO);
    short* enc_wf_hi  = (short*)(ws + OFF_EWFHI);
    short* enc_wf_lo  = (short*)(ws + OFF_EWFLO);
    short* hbm_hi     = (short*)(ws + OFF_HBMHI);
    short* hbm_lo     = (short*)(ws + OFF_HBMLO);
    short* hbe_hi     = (short*)(ws + OFF_HBEHI);
    short* hbe_lo     = (short*)(ws + OFF_HBELO);
    float* cbm        = ws + OFF_CBM;
    float* cbe        = ws + OFF_CBE;
    short* wihf_h     = (short*)(ws + OFF_WIHFH);
    short* wihf_l     = (short*)(ws + OFF_WIHFL);
    short* cw2h       = (short*)(ws + OFF_CW2H);
    short* cw2l       = (short*)(ws + OFF_CW2L);
    short* cw3h       = (short*)(ws + OFF_CW3H);
    short* cw3l       = (short*)(ws + OFF_CW3L);
    short* fcw_h      = (short*)(ws + OFF_FCWH);
    short* fcw_l      = (short*)(ws + OFF_FCWL);
    float* img_hidden = ws + OFF_IMGH;
    float* lang_in    = ws + OFF_LANGIN;
    float* enc_xW     = ws + OFF_ENCXW;
    float* enc_hs     = ws + OFF_ENCHS;
    float* lang_h     = ws + OFF_LANGH;
    short* hid_h      = (short*)(ws + OFF_HIDH);
    short* hid_l      = (short*)(ws + OFF_HIDL);
    float* mem_xW     = ws + OFF_MEMXW;
    float* mem_hs     = ws + OFF_MEMHS;
    float* enc_bc     = ws + OFF_ENCBC;
    float* mem_bc     = ws + OFF_MEMBC;
    float* head_w     = ws + OFF_HEADW;
    float* head_b     = ws + OFF_HEADB;

    prep_kernel<<<64, 256, 0, stream>>>(enc_bih, enc_bhh, mem_bih, mem_bhh,
                                        actor_w, actor_b, critic_w, critic_b,
                                        enc_bc, mem_bc, head_w, head_b);
    conv_frag_perm_kernel<<<20, 256, 0, stream>>>(conv2_w, cw2h, cw2l, 16, 5);
    conv_frag_perm_kernel<<<36, 256, 0, stream>>>(conv3_w, cw3h, cw3l, 32, 9);
    gemm_frag_kernel<<<1568, 256, 0, stream>>>(fc_w, fcw_h, fcw_l, 1568, 49, 16);
    conv_kernel<<<TBTOT, 256, 0, stream>>>(x_img, conv1_w, conv1_b,
                                           cw2h, cw2l, cw3h, cw3l, convAh, convAl);
    mfma_gemm<true><<<dim3(128, 4), 256, 0, stream>>>(convAh, convAl, fcw_h, fcw_l,
                                                      fc_b, img_hidden, 256, 1568, 49);
    // conv A region dead from here; LSTM fragments + state may now use it
    split_frag_kernel<<<65536, 256, 0, stream>>>(mem_Whh, mem_wf_hi, mem_wf_lo, 1024);
    split_frag_kernel<<<4096, 256, 0, stream>>>(enc_Whh, enc_wf_hi, enc_wf_lo, 256);
    gemm_frag_kernel<<<4608, 256, 0, stream>>>(mem_Wih, wihf_h, wihf_l, 288, 9, 256);
    init_state_kernel<<<128, 256, 0, stream>>>(enc_h0, enc_c0, hbe_hi, hbe_lo, cbe, BATCH * 256);
    init_state_kernel<<<512, 256, 0, stream>>>(mem_h0, mem_c0, hbm_hi, hbm_lo, cbm, BATCH * 1024);
    embed_kernel<<<1024, 256, 0, stream>>>(x_lang, emb, lang_in);
    gemm64<false><<<dim3(128, 16), 64, 0, stream>>>(lang_in, enc_Wih, enc_bc, enc_xW, TBTOT, 1024, 32);

    // ---- encoder scan (NB=32, dim3 grid) ----
    {
        int cur = 0;
        for (int st = 0; st < T_STEPS; ++st) {
            lstm_step_kernel<256, 32, false><<<dim3(16, 4), 256, 0, stream>>>(
                enc_xW + (size_t)st * BATCH * 1024, enc_wf_hi, enc_wf_lo, done + st,
                hbe_hi + (size_t)cur * (BATCH * 256), hbe_lo + (size_t)cur * (BATCH * 256),
                hbe_hi + (size_t)(cur ^ 1) * (BATCH * 256), hbe_lo + (size_t)(cur ^ 1) * (BATCH * 256),
                cbe, enc_hs + (size_t)st * BATCH * 256);
            cur ^= 1;
        }
    }
    // lang_h: thin-N fp32 GEMM (M=8192, N=32, K=256) — 1024 blocks
    gemm_thin<true, 32><<<1024, 256, 0, stream>>>(enc_hs, lemb_w, lemb_b, lang_h, 256);
    concat_kernel<<<TBTOT, 288, 0, stream>>>(img_hidden, lang_h, hid_h, hid_l);
    mfma_gemm<false><<<dim3(128, 64), 256, 0, stream>>>(hid_h, hid_l, wihf_h, wihf_l,
                                                        mem_bc, mem_xW, 4096, 288, 9);

    // ---- memory scan (NB=32, dim3 grid) ----
    {
        int cur = 0;
        for (int st = 0; st < T_STEPS; ++st) {
            lstm_step_kernel<1024, 32, true><<<dim3(64, 4), 256, 0, stream>>>(
                mem_xW + (size_t)st * BATCH * 4096, mem_wf_hi, mem_wf_lo, done + (size_t)st * BATCH,
                hbm_hi + (size_t)cur * (BATCH * 1024), hbm_lo + (size_t)cur * (BATCH * 1024),
                hbm_hi + (size_t)(cur ^ 1) * (BATCH * 1024), hbm_lo + (size_t)(cur ^ 1) * (BATCH * 1024),
                cbm, mem_hs + (size_t)st * BATCH * 1024);
            cur ^= 1;
        }
    }
    // head: thin-N fp32 GEMM (M=8192, N=16, K=1024) — 512 blocks
    gemm_thin<false, 16><<<512, 256, 0, stream>>>(mem_hs, head_w, head_b, (float*)d_out, 1024);
}

// Round 22
// 1454.064 us; speedup vs baseline: 1.1857x; 1.0110x over previous
//
#include <hip/hip_runtime.h>
#include <math.h>

#define T_STEPS 64
#define BATCH   128
#define TBTOT   8192

typedef __attribute__((ext_vector_type(8))) short bf16x8;
typedef __attribute__((ext_vector_type(4))) float f32x4;

// ---------------- workspace layout (float offsets) ----------------
// NOTE region lifetimes: [0,12845056) holds convAh/convAl during conv+fc, then is
// reused for LSTM fragments + state. State init MUST run after the fc GEMM.
static const size_t OFF_CONVH  = 0;              // [8192*1568] bf16 hi
static const size_t OFF_CONVL  = 6422528;        // [8192*1568] bf16 lo
static const size_t OFF_MWFHI  = 0;              // [4096*1024] bf16 (phase 2)
static const size_t OFF_MWFLO  = 2097152;
static const size_t OFF_EWFHI  = 4194304;        // [1024*256] bf16
static const size_t OFF_EWFLO  = 4325376;
static const size_t OFF_HBMHI  = 4456448;        // [2][128][1024] bf16
static const size_t OFF_HBMLO  = 4587520;
static const size_t OFF_HBEHI  = 4718592;        // [2][128][256] bf16
static const size_t OFF_HBELO  = 4734976;
static const size_t OFF_CBM    = 4767744;        // [128][1024] f32
static const size_t OFF_CBE    = 4898816;        // [128][256] f32
static const size_t OFF_WIHFH  = 4931584;        // [4096*288] bf16
static const size_t OFF_WIHFL  = 5521408;
static const size_t OFF_IMGH   = 12845056;       // [8192][256]
static const size_t OFF_LANGIN = 14942208;       // [8192][32]
static const size_t OFF_ENCXW  = 15204352;       // [8192][1024]
static const size_t OFF_ENCHS  = 23592960;       // [8192][256]
static const size_t OFF_LANGH  = 25690112;       // [8192][32]
static const size_t OFF_HIDH   = 25952256;       // [8192*288] bf16 hi
static const size_t OFF_HIDL   = 27131904;       // [8192*288] bf16 lo
static const size_t OFF_MEMXW  = 28311552;       // [8192][4096]
static const size_t OFF_CW2H   = 28311552;       // 5120 shorts
static const size_t OFF_CW2L   = 28314112;
static const size_t OFF_CW3H   = 28316672;       // 9216 shorts
static const size_t OFF_CW3L   = 28321280;
static const size_t OFF_FCWH   = 28325888;       // [256*1568] bf16
static const size_t OFF_FCWL   = 28526592;
static const size_t OFF_MEMHS  = 61865984;       // [8192][1024]
static const size_t OFF_ENCBC  = 70582272;       // [1024]
static const size_t OFF_MEMBC  = 70583296;       // [4096]
static const size_t OFF_HEADW  = 70587392;       // [16][1024]
static const size_t OFF_HEADB  = 70603776;       // [16]

__device__ __forceinline__ float fast_sigm(float x) { return 1.0f / (1.0f + __expf(-x)); }
__device__ __forceinline__ float fast_tanh(float x) { return 2.0f / (1.0f + __expf(-2.0f * x)) - 1.0f; }

__device__ __forceinline__ short f32_to_bf16_rne(float x) {
    unsigned u = __float_as_uint(x);
    unsigned r = (u + 0x7fffu + ((u >> 16) & 1u)) >> 16;
    return (short)r;
}
__device__ __forceinline__ float bf16s_to_f32(short s) {
    return __uint_as_float(((unsigned)(unsigned short)s) << 16);
}

// ---------------- prep ----------------
__global__ void prep_kernel(const float* __restrict__ enc_bih, const float* __restrict__ enc_bhh,
                            const float* __restrict__ mem_bih, const float* __restrict__ mem_bhh,
                            const float* __restrict__ actor_w, const float* __restrict__ actor_b,
                            const float* __restrict__ critic_w, const float* __restrict__ critic_b,
                            float* __restrict__ enc_bc, float* __restrict__ mem_bc,
                            float* __restrict__ head_w, float* __restrict__ head_b) {
    int g = blockIdx.x * 256 + threadIdx.x;
    if (g < 1024)  enc_bc[g] = enc_bih[g] + enc_bhh[g];
    if (g < 4096)  mem_bc[g] = mem_bih[g] + mem_bhh[g];
    if (g < 16384) { int j = g >> 10, k = g & 1023; head_w[g] = (j < 15) ? actor_w[j * 1024 + k] : critic_w[k]; }
    if (g < 16)    head_b[g] = (g < 15) ? actor_b[g] : critic_b[0];
}

// ---------------- init LSTM state (runs AFTER fc GEMM frees the region) ----------------
__global__ void init_state_kernel(const float* __restrict__ h0, const float* __restrict__ c0,
                                  short* __restrict__ hhi, short* __restrict__ hlo,
                                  float* __restrict__ cb, int n) {
    int g = blockIdx.x * 256 + threadIdx.x;
    if (g < n) {
        float v = h0[g];
        short a = f32_to_bf16_rne(v);
        hhi[g] = a;
        hlo[g] = f32_to_bf16_rne(v - bf16s_to_f32(a));
        cb[g] = c0[g];
    }
}

// ---------------- split Whh into MFMA-fragment-ordered bf16 hi/lo ----------------
__global__ void split_frag_kernel(const float* __restrict__ W, short* __restrict__ hi,
                                  short* __restrict__ lo, int H) {
    size_t f = (size_t)blockIdx.x * 256 + threadIdx.x;
    size_t total = (size_t)4 * H * H;
    if (f >= total) return;
    int e    = (int)(f & 7);
    int lane = (int)((f >> 3) & 63);
    size_t rest = f >> 9;
    int nks = H >> 5;
    int ks  = (int)(rest % nks);
    int qjt = (int)(rest / nks);
    int njt = H >> 4;
    int qq = qjt / njt, jt = qjt - qq * njt;
    int n = qq * H + jt * 16 + (lane & 15);
    int k = ks * 32 + (lane >> 4) * 8 + e;
    float w = W[(size_t)n * H + k];
    short a = f32_to_bf16_rne(w);
    short b = f32_to_bf16_rne(w - bf16s_to_f32(a));
    hi[f] = a; lo[f] = b;
}

// ---------------- generic GEMM weight frags (row-major K) ----------------
__global__ void gemm_frag_kernel(const float* __restrict__ W, short* __restrict__ hi,
                                 short* __restrict__ lo, int Kv, int nks, int ntot) {
    int f = blockIdx.x * 256 + threadIdx.x;
    int total = ntot * nks * 512;
    if (f >= total) return;
    int e    = f & 7;
    int lane = (f >> 3) & 63;
    int rest = f >> 9;
    int ks   = rest % nks;
    int nt   = rest / nks;
    int n = nt * 16 + (lane & 15);
    int k = ks * 32 + (lane >> 4) * 8 + e;
    float w = (k < Kv) ? W[(size_t)n * Kv + k] : 0.0f;
    short a = f32_to_bf16_rne(w);
    short b = f32_to_bf16_rne(w - bf16s_to_f32(a));
    hi[f] = a; lo[f] = b;
}

// ---------------- conv weight frags, TAP-MAJOR permuted K: k' = tap*ICN + ic ----------------
__global__ void conv_frag_perm_kernel(const float* __restrict__ W, short* __restrict__ hi,
                                      short* __restrict__ lo, int ICN, int nks) {
    int f = blockIdx.x * 256 + threadIdx.x;
    int total = 2 * nks * 512;
    if (f >= total) return;
    int e    = f & 7;
    int lane = (f >> 3) & 63;
    int rest = f >> 9;
    int ks   = rest % nks;
    int nt   = rest / nks;
    int n  = nt * 16 + (lane & 15);
    int kp = ks * 32 + (lane >> 4) * 8 + e;
    int Kv = ICN * 9;
    float w = 0.0f;
    if (kp < Kv) {
        int tap = kp / ICN, ic = kp % ICN;
        w = W[(size_t)n * Kv + ic * 9 + tap];
    }
    short a = f32_to_bf16_rne(w);
    short b = f32_to_bf16_rne(w - bf16s_to_f32(a));
    hi[f] = a; lo[f] = b;
}

// ---------------- MFMA split-bf16 GEMM, 64x64 tile ----------------
template <bool RELU>
__global__ __launch_bounds__(256) void mfma_gemm(
        const short* __restrict__ Ah, const short* __restrict__ Al,
        const short* __restrict__ Wfh, const short* __restrict__ Wfl,
        const float* __restrict__ bias, float* __restrict__ C,
        int N, int K, int KS) {
    const int t = threadIdx.x, lane = t & 63, wv = t >> 6;
    const int m0 = blockIdx.x * 64, n0 = blockIdx.y * 64;
    const int pr = m0 + wv * 16 + (lane & 15);
    const size_t abase = (size_t)pr * K + ((lane >> 4) << 3);
    const int ntg0 = n0 >> 4;
    f32x4 acc0 = {0.f,0.f,0.f,0.f}, acc1 = {0.f,0.f,0.f,0.f};
    f32x4 acc2 = {0.f,0.f,0.f,0.f}, acc3 = {0.f,0.f,0.f,0.f};
    for (int ks = 0; ks < KS; ++ks) {
        bf16x8 ah = *(const bf16x8*)&Ah[abase + (size_t)ks * 32];
        bf16x8 al = *(const bf16x8*)&Al[abase + (size_t)ks * 32];
        const bf16x8* bh0 = (const bf16x8*)Wfh + ((size_t)ntg0 * KS + ks) * 64 + lane;
        const bf16x8* bl0 = (const bf16x8*)Wfl + ((size_t)ntg0 * KS + ks) * 64 + lane;
        bf16x8 bh, bl;
        bh = bh0[0];            bl = bl0[0];
        acc0 = __builtin_amdgcn_mfma_f32_16x16x32_bf16(ah, bh, acc0, 0, 0, 0);
        acc0 = __builtin_amdgcn_mfma_f32_16x16x32_bf16(ah, bl, acc0, 0, 0, 0);
        acc0 = __builtin_amdgcn_mfma_f32_16x16x32_bf16(al, bh, acc0, 0, 0, 0);
        bh = bh0[(size_t)KS * 64]; bl = bl0[(size_t)KS * 64];
        acc1 = __builtin_amdgcn_mfma_f32_16x16x32_bf16(ah, bh, acc1, 0, 0, 0);
        acc1 = __builtin_amdgcn_mfma_f32_16x16x32_bf16(ah, bl, acc1, 0, 0, 0);
        acc1 = __builtin_amdgcn_mfma_f32_16x16x32_bf16(al, bh, acc1, 0, 0, 0);
        bh = bh0[(size_t)KS * 128]; bl = bl0[(size_t)KS * 128];
        acc2 = __builtin_amdgcn_mfma_f32_16x16x32_bf16(ah, bh, acc2, 0, 0, 0);
        acc2 = __builtin_amdgcn_mfma_f32_16x16x32_bf16(ah, bl, acc2, 0, 0, 0);
        acc2 = __builtin_amdgcn_mfma_f32_16x16x32_bf16(al, bh, acc2, 0, 0, 0);
        bh = bh0[(size_t)KS * 192]; bl = bl0[(size_t)KS * 192];
        acc3 = __builtin_amdgcn_mfma_f32_16x16x32_bf16(ah, bh, acc3, 0, 0, 0);
        acc3 = __builtin_amdgcn_mfma_f32_16x16x32_bf16(ah, bl, acc3, 0, 0, 0);
        acc3 = __builtin_amdgcn_mfma_f32_16x16x32_bf16(al, bh, acc3, 0, 0, 0);
    }
    const int rbase = m0 + wv * 16 + ((lane >> 4) << 2);
    #pragma unroll
    for (int nt = 0; nt < 4; ++nt) {
        f32x4 a = (nt == 0) ? acc0 : (nt == 1) ? acc1 : (nt == 2) ? acc2 : acc3;
        int n = n0 + nt * 16 + (lane & 15);
        float bv = bias[n];
        #pragma unroll
        for (int r = 0; r < 4; ++r) {
            float v = a[r] + bv;
            if (RELU) v = fmaxf(v, 0.0f);
            C[(size_t)(rbase + r) * N + n] = v;
        }
    }
}

// ---------------- thin-N fp32 GEMM: thread per output, full-machine grid ----------------
template <bool RELU, int N_>
__global__ __launch_bounds__(256) void gemm_thin(const float* __restrict__ A,
                                                 const float* __restrict__ W,
                                                 const float* __restrict__ bias,
                                                 float* __restrict__ C, int K) {
    int gid = blockIdx.x * 256 + threadIdx.x;
    int m = gid / N_, n = gid - m * N_;
    const float4* a = (const float4*)(A + (size_t)m * K);
    const float4* w = (const float4*)(W + (size_t)n * K);
    float acc = 0.0f;
    for (int k = 0; k < (K >> 2); ++k) {
        float4 av = a[k], wv = w[k];
        acc += av.x * wv.x + av.y * wv.y + av.z * wv.z + av.w * wv.w;
    }
    float v = acc + bias[n];
    if (RELU) v = fmaxf(v, 0.0f);
    C[(size_t)m * N_ + n] = v;
}

// ---------------- conv stack v6: no image staging (conv1 reads global, high occupancy) ----------------
__global__ __launch_bounds__(256) void conv_kernel(const float* __restrict__ x,
        const float* __restrict__ w1, const float* __restrict__ b1,
        const short* __restrict__ w2fh, const short* __restrict__ w2fl,
        const short* __restrict__ w3fh, const short* __restrict__ w3fl,
        short* __restrict__ outh, short* __restrict__ outl) {
    __shared__ short sp[12288];                  // 24576 B total
    short* o1ch  = sp;                           // [121][24]
    short* o1cl  = sp + 2904;
    short* o2ch  = sp + 5808;                    // [81][40]
    short* o2cl  = sp + 9048;                    // ends at 12288
    const int t = threadIdx.x, lane = t & 63;
    const int wv = t >> 6;
    const int g  = lane >> 4;
    const size_t img = blockIdx.x;
    const bf16x8 zero8 = {0, 0, 0, 0, 0, 0, 0, 0};
    const float* xi = x + img * 9801;

    {   // conv1: direct global reads (waves 2-3 duplicate waves 0-1 -> L1 hits)
        const int cg2 = __builtin_amdgcn_readfirstlane(t >> 7);
        const int p = t & 127;
        if (p < 121) {
            int i = p / 11, j = p - i * 11;
            float acc[8];
            #pragma unroll
            for (int cc = 0; cc < 8; ++cc) acc[cc] = b1[cg2 * 8 + cc];
            for (int ky = 0; ky < 9; ++ky) {
                const float* irow = xi + (i * 9 + ky) * 99 + j * 9;
                float row[9];
                #pragma unroll
                for (int kx = 0; kx < 9; ++kx) row[kx] = irow[kx] * (1.0f / 255.0f);
                #pragma unroll
                for (int cc = 0; cc < 8; ++cc) {
                    const float* wr = w1 + (cg2 * 8 + cc) * 81 + ky * 9;
                    #pragma unroll
                    for (int kx = 0; kx < 9; ++kx) acc[cc] += wr[kx] * row[kx];
                }
            }
            bf16x8 vh, vl;
            #pragma unroll
            for (int cc = 0; cc < 8; ++cc) {
                float v = fmaxf(acc[cc], 0.0f);
                short h = f32_to_bf16_rne(v);
                vh[cc] = h;
                vl[cc] = f32_to_bf16_rne(v - bf16s_to_f32(h));
            }
            *(bf16x8*)&o1ch[p * 24 + cg2 * 8] = vh;
            *(bf16x8*)&o1cl[p * 24 + cg2 * 8] = vl;
        }
    }
    __syncthreads();

    {   // conv2 MFMA: k' = tap*16 + ic; fragment = ONE b128 from o1c
        const int ic0 = (g & 1) * 8;
        int toff2[5];
        #pragma unroll
        for (int ks = 0; ks < 5; ++ks) {
            int tap = 2 * ks + (g >> 1);
            if (tap > 8) tap = 8;
            toff2[ks] = (tap / 3) * 11 + (tap % 3);
        }
        #pragma unroll
        for (int i = 0; i < 3; ++i) {
            int tau = wv + 4 * i;
            int Mt = tau >> 1, Nt = tau & 1;
            int p = Mt * 16 + (lane & 15);
            int prow = (p / 9) * 11 + (p % 9);
            if (p >= 81) prow = 0;
            f32x4 acc = {0.f, 0.f, 0.f, 0.f};
            #pragma unroll
            for (int ks = 0; ks < 5; ++ks) {
                int ad = (prow + toff2[ks]) * 24 + ic0;
                bf16x8 ah = *(const bf16x8*)&o1ch[ad];
                bf16x8 al = *(const bf16x8*)&o1cl[ad];
                if (ks == 4 && g >= 2) { ah = zero8; al = zero8; }
                bf16x8 bh = ((const bf16x8*)w2fh)[(Nt * 5 + ks) * 64 + lane];
                bf16x8 bl = ((const bf16x8*)w2fl)[(Nt * 5 + ks) * 64 + lane];
                acc = __builtin_amdgcn_mfma_f32_16x16x32_bf16(ah, bh, acc, 0, 0, 0);
                acc = __builtin_amdgcn_mfma_f32_16x16x32_bf16(ah, bl, acc, 0, 0, 0);
                acc = __builtin_amdgcn_mfma_f32_16x16x32_bf16(al, bh, acc, 0, 0, 0);
            }
            int c = Nt * 16 + (lane & 15);
            #pragma unroll
            for (int r = 0; r < 4; ++r) {
                int pp = Mt * 16 + ((lane >> 4) << 2) + r;
                if (pp < 81) {
                    float v = fmaxf(acc[r], 0.0f);
                    short h = f32_to_bf16_rne(v);
                    o2ch[pp * 40 + c] = h;
                    o2cl[pp * 40 + c] = f32_to_bf16_rne(v - bf16s_to_f32(h));
                }
            }
        }
    }
    __syncthreads();

    {   // conv3 MFMA: k' = tap*32 + ic; K=288 exact
        short* ogh = outh + img * 1568;
        short* ogl = outl + img * 1568;
        #pragma unroll
        for (int i = 0; i < 2; ++i) {
            int tau = wv + 4 * i;
            int Mt = tau >> 1, Nt = tau & 1;
            int p = Mt * 16 + (lane & 15);
            int prow = (p / 7) * 9 + (p % 7);
            if (p >= 49) prow = 0;
            f32x4 acc = {0.f, 0.f, 0.f, 0.f};
            #pragma unroll
            for (int ks = 0; ks < 9; ++ks) {
                int toff = (ks / 3) * 9 + (ks % 3);
                int ad = (prow + toff) * 40 + g * 8;
                bf16x8 ah = *(const bf16x8*)&o2ch[ad];
                bf16x8 al = *(const bf16x8*)&o2cl[ad];
                bf16x8 bh = ((const bf16x8*)w3fh)[(Nt * 9 + ks) * 64 + lane];
                bf16x8 bl = ((const bf16x8*)w3fl)[(Nt * 9 + ks) * 64 + lane];
                acc = __builtin_amdgcn_mfma_f32_16x16x32_bf16(ah, bh, acc, 0, 0, 0);
                acc = __builtin_amdgcn_mfma_f32_16x16x32_bf16(ah, bl, acc, 0, 0, 0);
                acc = __builtin_amdgcn_mfma_f32_16x16x32_bf16(al, bh, acc, 0, 0, 0);
            }
            int c = Nt * 16 + (lane & 15);
            #pragma unroll
            for (int r = 0; r < 4; ++r) {
                int pp = Mt * 16 + ((lane >> 4) << 2) + r;
                if (pp < 49) {
                    float v = fmaxf(acc[r], 0.0f);
                    short h = f32_to_bf16_rne(v);
                    ogh[c * 49 + pp] = h;
                    ogl[c * 49 + pp] = f32_to_bf16_rne(v - bf16s_to_f32(h));
                }
            }
        }
    }
}

// ---------------- generic tiled fp32 GEMM (enc_xW case) ----------------
template <bool RELU>
__global__ __launch_bounds__(64) void gemm64(const float* __restrict__ A, const float* __restrict__ W,
                                             const float* __restrict__ bias, float* __restrict__ C,
                                             int M, int N, int K) {
    __shared__ float At[32][68];
    __shared__ float Wt[32][68];
    const int m0 = blockIdx.x * 64, n0 = blockIdx.y * 64;
    const int t = threadIdx.x;
    const int tx = t & 7, ty = t >> 3;
    float acc[8][8] = {};
    for (int kc = 0; kc < K; kc += 32) {
        #pragma unroll
        for (int i = 0; i < 8; ++i) {
            int e = t + i * 64;
            int row = e >> 3, c4 = (e & 7) * 4;
            float4 v = *(const float4*)&A[(size_t)(m0 + row) * K + kc + c4];
            At[c4 + 0][row] = v.x; At[c4 + 1][row] = v.y; At[c4 + 2][row] = v.z; At[c4 + 3][row] = v.w;
            int n = n0 + row;
            float4 wv = make_float4(0.f, 0.f, 0.f, 0.f);
            if (n < N) wv = *(const float4*)&W[(size_t)n * K + kc + c4];
            Wt[c4 + 0][row] = wv.x; Wt[c4 + 1][row] = wv.y; Wt[c4 + 2][row] = wv.z; Wt[c4 + 3][row] = wv.w;
        }
        __syncthreads();
        #pragma unroll
        for (int kk = 0; kk < 32; ++kk) {
            float4 a0 = *(const float4*)&At[kk][ty * 8];
            float4 a1 = *(const float4*)&At[kk][ty * 8 + 4];
            float4 b0 = *(const float4*)&Wt[kk][tx * 8];
            float4 b1 = *(const float4*)&Wt[kk][tx * 8 + 4];
            float a[8] = {a0.x, a0.y, a0.z, a0.w, a1.x, a1.y, a1.z, a1.w};
            float b[8] = {b0.x, b0.y, b0.z, b0.w, b1.x, b1.y, b1.z, b1.w};
            #pragma unroll
            for (int i = 0; i < 8; ++i)
                #pragma unroll
                for (int j = 0; j < 8; ++j) acc[i][j] += a[i] * b[j];
        }
        __syncthreads();
    }
    #pragma unroll
    for (int i = 0; i < 8; ++i) {
        int m = m0 + ty * 8 + i;
        #pragma unroll
        for (int j = 0; j < 8; ++j) {
            int n = n0 + tx * 8 + j;
            if (n < N) {
                float v = acc[i][j] + bias[n];
                if (RELU) v = fmaxf(v, 0.0f);
                C[(size_t)m * N + n] = v;
            }
        }
    }
}

// ---------------- embedding ----------------
__global__ void embed_kernel(const int* __restrict__ lang, const float* __restrict__ emb,
                             float* __restrict__ out) {
    int g = blockIdx.x * 256 + threadIdx.x;
    if (g < TBTOT * 32) { int r = g >> 5, c = g & 31; out[g] = emb[lang[r] * 32 + c]; }
}

// ---------------- concat -> split bf16 hidden ----------------
__global__ void concat_kernel(const float* __restrict__ img_h, const float* __restrict__ lang_h,
                              short* __restrict__ outh, short* __restrict__ outl) {
    int r = blockIdx.x, c = threadIdx.x;
    float v = (c < 256) ? img_h[r * 256 + c] : lang_h[r * 32 + (c - 256)];
    short h = f32_to_bf16_rne(v);
    outh[r * 288 + c] = h;
    outl[r * 288 + c] = f32_to_bf16_rne(v - bf16s_to_f32(h));
}

// ---------------- ONE LSTM STEP, NB batch rows per block (dim3 grid) ----------------
template <int H, int NB, bool PER_ENV>
__global__ __launch_bounds__(256) void lstm_step_kernel(
        const float* __restrict__ xw_s,    // [B][4H] for this step
        const short* __restrict__ wf_hi,
        const short* __restrict__ wf_lo,
        const float* __restrict__ done_s,  // PER_ENV ? [B] : [1] scalar
        const short* __restrict__ hs_hi, const short* __restrict__ hs_lo,
        short* __restrict__ hd_hi, short* __restrict__ hd_lo,
        float* __restrict__ cbuf,
        float* __restrict__ hs_out) {
    constexpr int CK   = 8192 / NB;
    constexpr int SEGS = CK / 8;
    constexpr int NMT  = NB / 16;
    constexpr int NCH  = H / CK;
    constexpr int KSL  = CK / 32;
    __shared__ bf16x8 lsA[2][1024];
    __shared__ float  gbuf[4][NB][16];
    const int t    = threadIdx.x;
    const int lane = t & 63;
    const int q    = t >> 6;
    const int jt   = blockIdx.x;
    const int j0   = jt * 16;
    const int b0   = blockIdx.y * NB;
    const int jl   = t & 15, bl = (t >> 4) & 15;
    const int jg   = j0 + jl;
    const int njt  = H >> 4, nks = H >> 5;

    const float m_step = PER_ENV ? 0.0f : (1.0f - done_s[0]);

    float xg[NMT][4], m_e[NMT];
    #pragma unroll
    for (int e = 0; e < NMT; ++e) {
        int bgl = b0 + bl + e * 16;
        const float* xr = xw_s + (size_t)bgl * (4 * H);
        #pragma unroll
        for (int g4 = 0; g4 < 4; ++g4) xg[e][g4] = xr[g4 * H + jg];
        m_e[e] = PER_ENV ? (1.0f - done_s[bgl]) : m_step;
    }

    f32x4 acc[NMT];
    #pragma unroll
    for (int m = 0; m < NMT; ++m) acc[m] = (f32x4){0.f, 0.f, 0.f, 0.f};
    const bf16x8* bfh = (const bf16x8*)wf_hi + (size_t)(q * njt + jt) * nks * 64;
    const bf16x8* bfl = (const bf16x8*)wf_lo + (size_t)(q * njt + jt) * nks * 64;
    const bf16x8 zero8 = {0, 0, 0, 0, 0, 0, 0, 0};

    for (int cch = 0; cch < NCH; ++cch) {
        const int k0 = cch * CK;
        #pragma unroll
        for (int i = 0; i < 4; ++i) {
            int idx = i * 256 + t;
            int row = idx / SEGS, seg = idx % SEGS;
            float m = PER_ENV ? (1.0f - done_s[b0 + row]) : m_step;
            int slot = seg * NB + ((row ^ seg) & (NB - 1));
            bf16x8 vh = *(const bf16x8*)&hs_hi[(size_t)(b0 + row) * H + k0 + seg * 8];
            bf16x8 vl = *(const bf16x8*)&hs_lo[(size_t)(b0 + row) * H + k0 + seg * 8];
            if (m == 0.0f) { vh = zero8; vl = zero8; }
            lsA[0][slot] = vh;
            lsA[1][slot] = vl;
        }
        __syncthreads();
        #pragma unroll
        for (int ksl = 0; ksl < KSL; ++ksl) {
            int ks = cch * KSL + ksl;
            bf16x8 b_hi = bfh[(size_t)ks * 64 + lane];
            bf16x8 b_lo = bfl[(size_t)ks * 64 + lane];
            int kgrp = ksl * 4 + (lane >> 4);
            #pragma unroll
            for (int mt = 0; mt < NMT; ++mt) {
                int row = mt * 16 + (lane & 15);
                int slot = kgrp * NB + ((row ^ kgrp) & (NB - 1));
                bf16x8 ah = lsA[0][slot];
                bf16x8 al = lsA[1][slot];
                acc[mt] = __builtin_amdgcn_mfma_f32_16x16x32_bf16(ah, b_hi, acc[mt], 0, 0, 0);
                acc[mt] = __builtin_amdgcn_mfma_f32_16x16x32_bf16(ah, b_lo, acc[mt], 0, 0, 0);
                acc[mt] = __builtin_amdgcn_mfma_f32_16x16x32_bf16(al, b_hi, acc[mt], 0, 0, 0);
            }
        }
        __syncthreads();
    }

    // gate partial write (C/D layout: col=lane&15, row=(lane>>4)*4+r)
    #pragma unroll
    for (int mt = 0; mt < NMT; ++mt)
        #pragma unroll
        for (int r = 0; r < 4; ++r)
            gbuf[q][mt * 16 + ((lane >> 4) << 2) + r][lane & 15] = acc[mt][r];
    __syncthreads();

    #pragma unroll
    for (int e = 0; e < NMT; ++e) {
        int b_loc = bl + e * 16;
        int bgl = b0 + b_loc;
        float m = m_e[e];
        float gi = gbuf[0][b_loc][jl] + xg[e][0];
        float gf = gbuf[1][b_loc][jl] + xg[e][1];
        float gg = gbuf[2][b_loc][jl] + xg[e][2];
        float go = gbuf[3][b_loc][jl] + xg[e][3];
        size_t ci = (size_t)bgl * H + jg;
        float cc = fast_sigm(gf) * (cbuf[ci] * m) + fast_sigm(gi) * fast_tanh(gg);
        float hh = fast_sigm(go) * fast_tanh(cc);
        cbuf[ci] = cc;
        hs_out[ci] = hh;
        short hhi = f32_to_bf16_rne(hh);
        short hlo = f32_to_bf16_rne(hh - bf16s_to_f32(hhi));
        hd_hi[ci] = hhi;
        hd_lo[ci] = hlo;
    }
}

extern "C" void kernel_launch(void* const* d_in, const int* in_sizes, int n_in,
                              void* d_out, int out_size, void* d_ws, size_t ws_size,
                              hipStream_t stream) {
    const float* x_img    = (const float*)d_in[0];
    const int*   x_lang   = (const int*)d_in[1];
    const float* done     = (const float*)d_in[2];
    const float* enc_h0   = (const float*)d_in[3];
    const float* enc_c0   = (const float*)d_in[4];
    const float* mem_h0   = (const float*)d_in[5];
    const float* mem_c0   = (const float*)d_in[6];
    const float* emb      = (const float*)d_in[7];
    const float* conv1_w  = (const float*)d_in[8];
    const float* conv1_b  = (const float*)d_in[9];
    const float* conv2_w  = (const float*)d_in[10];
    const float* conv2_b  = (const float*)d_in[11];
    const float* conv3_w  = (const float*)d_in[12];
    const float* conv3_b  = (const float*)d_in[13];
    const float* fc_w     = (const float*)d_in[14];
    const float* fc_b     = (const float*)d_in[15];
    const float* enc_Wih  = (const float*)d_in[16];
    const float* enc_Whh  = (const float*)d_in[17];
    const float* enc_bih  = (const float*)d_in[18];
    const float* enc_bhh  = (const float*)d_in[19];
    const float* lemb_w   = (const float*)d_in[20];
    const float* lemb_b   = (const float*)d_in[21];
    const float* mem_Wih  = (const float*)d_in[22];
    const float* mem_Whh  = (const float*)d_in[23];
    const float* mem_bih  = (const float*)d_in[24];
    const float* mem_bhh  = (const float*)d_in[25];
    const float* actor_w  = (const float*)d_in[26];
    const float* actor_b  = (const float*)d_in[27];
    const float* critic_w = (const float*)d_in[28];
    const float* critic_b = (const float*)d_in[29];

    float* ws = (float*)d_ws;
    short* convAh     = (short*)(ws + OFF_CONVH);
    short* convAl     = (short*)(ws + OFF_CONVL);
    short* mem_wf_hi  = (short*)(ws + OFF_MWFHI);
    short* mem_wf_lo  = (short*)(ws + OFF_MWFLO);
    short* enc_wf_hi  = (short*)(ws + OFF_EWFHI);
    short* enc_wf_lo  = (short*)(ws + OFF_EWFLO);
    short* hbm_hi     = (short*)(ws + OFF_HBMHI);
    short* hbm_lo     = (short*)(ws + OFF_HBMLO);
    short* hbe_hi     = (short*)(ws + OFF_HBEHI);
    short* hbe_lo     = (short*)(ws + OFF_HBELO);
    float* cbm        = ws + OFF_CBM;
    float* cbe        = ws + OFF_CBE;
    short* wihf_h     = (short*)(ws + OFF_WIHFH);
    short* wihf_l     = (short*)(ws + OFF_WIHFL);
    short* cw2h       = (short*)(ws + OFF_CW2H);
    short* cw2l       = (short*)(ws + OFF_CW2L);
    short* cw3h       = (short*)(ws + OFF_CW3H);
    short* cw3l       = (short*)(ws + OFF_CW3L);
    short* fcw_h      = (short*)(ws + OFF_FCWH);
    short* fcw_l      = (short*)(ws + OFF_FCWL);
    float* img_hidden = ws + OFF_IMGH;
    float* lang_in    = ws + OFF_LANGIN;
    float* enc_xW     = ws + OFF_ENCXW;
    float* enc_hs     = ws + OFF_ENCHS;
    float* lang_h     = ws + OFF_LANGH;
    short* hid_h      = (short*)(ws + OFF_HIDH);
    short* hid_l      = (short*)(ws + OFF_HIDL);
    float* mem_xW     = ws + OFF_MEMXW;
    float* mem_hs     = ws + OFF_MEMHS;
    float* enc_bc     = ws + OFF_ENCBC;
    float* mem_bc     = ws + OFF_MEMBC;
    float* head_w     = ws + OFF_HEADW;
    float* head_b     = ws + OFF_HEADB;

    prep_kernel<<<64, 256, 0, stream>>>(enc_bih, enc_bhh, mem_bih, mem_bhh,
                                        actor_w, actor_b, critic_w, critic_b,
                                        enc_bc, mem_bc, head_w, head_b);
    conv_frag_perm_kernel<<<20, 256, 0, stream>>>(conv2_w, cw2h, cw2l, 16, 5);
    conv_frag_perm_kernel<<<36, 256, 0, stream>>>(conv3_w, cw3h, cw3l, 32, 9);
    gemm_frag_kernel<<<1568, 256, 0, stream>>>(fc_w, fcw_h, fcw_l, 1568, 49, 16);
    conv_kernel<<<TBTOT, 256, 0, stream>>>(x_img, conv1_w, conv1_b,
                                           cw2h, cw2l, cw3h, cw3l, convAh, convAl);
    mfma_gemm<true><<<dim3(128, 4), 256, 0, stream>>>(convAh, convAl, fcw_h, fcw_l,
                                                      fc_b, img_hidden, 256, 1568, 49);
    // conv A region dead from here; LSTM fragments + state may now use it
    // exact grids: mem Whh 4*1024*1024/256 = 16384; enc Whh 4*256*256/256 = 1024
    split_frag_kernel<<<16384, 256, 0, stream>>>(mem_Whh, mem_wf_hi, mem_wf_lo, 1024);
    split_frag_kernel<<<1024, 256, 0, stream>>>(enc_Whh, enc_wf_hi, enc_wf_lo, 256);
    gemm_frag_kernel<<<4608, 256, 0, stream>>>(mem_Wih, wihf_h, wihf_l, 288, 9, 256);
    init_state_kernel<<<128, 256, 0, stream>>>(enc_h0, enc_c0, hbe_hi, hbe_lo, cbe, BATCH * 256);
    init_state_kernel<<<512, 256, 0, stream>>>(mem_h0, mem_c0, hbm_hi, hbm_lo, cbm, BATCH * 1024);
    embed_kernel<<<1024, 256, 0, stream>>>(x_lang, emb, lang_in);
    gemm64<false><<<dim3(128, 16), 64, 0, stream>>>(lang_in, enc_Wih, enc_bc, enc_xW, TBTOT, 1024, 32);

    // ---- encoder scan (NB=32, dim3 grid) ----
    {
        int cur = 0;
        for (int st = 0; st < T_STEPS; ++st) {
            lstm_step_kernel<256, 32, false><<<dim3(16, 4), 256, 0, stream>>>(
                enc_xW + (size_t)st * BATCH * 1024, enc_wf_hi, enc_wf_lo, done + st,
                hbe_hi + (size_t)cur * (BATCH * 256), hbe_lo + (size_t)cur * (BATCH * 256),
                hbe_hi + (size_t)(cur ^ 1) * (BATCH * 256), hbe_lo + (size_t)(cur ^ 1) * (BATCH * 256),
                cbe, enc_hs + (size_t)st * BATCH * 256);
            cur ^= 1;
        }
    }
    // lang_h: thin-N fp32 GEMM (M=8192, N=32, K=256) — 1024 blocks
    gemm_thin<true, 32><<<1024, 256, 0, stream>>>(enc_hs, lemb_w, lemb_b, lang_h, 256);
    concat_kernel<<<TBTOT, 288, 0, stream>>>(img_hidden, lang_h, hid_h, hid_l);
    mfma_gemm<false><<<dim3(128, 64), 256, 0, stream>>>(hid_h, hid_l, wihf_h, wihf_l,
                                                        mem_bc, mem_xW, 4096, 288, 9);

    // ---- memory scan (NB=32, dim3 grid) ----
    {
        int cur = 0;
        for (int st = 0; st < T_STEPS; ++st) {
            lstm_step_kernel<1024, 32, true><<<dim3(64, 4), 256, 0, stream>>>(
                mem_xW + (size_t)st * BATCH * 4096, mem_wf_hi, mem_wf_lo, done + (size_t)st * BATCH,
                hbm_hi + (size_t)cur * (BATCH * 1024), hbm_lo + (size_t)cur * (BATCH * 1024),
                hbm_hi + (size_t)(cur ^ 1) * (BATCH * 1024), hbm_lo + (size_t)(cur ^ 1) * (BATCH * 1024),
                cbm, mem_hs + (size_t)st * BATCH * 1024);
            cur ^= 1;
        }
    }
    // head: thin-N fp32 GEMM (M=8192, N=16, K=1024) — 512 blocks
    gemm_thin<false, 16><<<512, 256, 0, stream>>>(mem_hs, head_w, head_b, (float*)d_out, 1024);
}